// Round 2
// baseline (429.421 us; speedup 1.0000x reference)
//
#include <hip/hip_runtime.h>
#include <cstdint>
#include <cstddef>

typedef unsigned short u16;
typedef unsigned int   u32;
typedef __attribute__((ext_vector_type(8))) short short8;
typedef __attribute__((ext_vector_type(4))) float floatx4;

__device__ __forceinline__ float asf(u32 u){ union{u32 u; float f;} v; v.u=u; return v.f; }
__device__ __forceinline__ u32 asu(float f){ union{float f; u32 u;} v; v.f=f; return v.u; }
__device__ __forceinline__ float bf2f(u16 u){ return asf(((u32)u)<<16); }
__device__ __forceinline__ u16 f2bf(float f){ u32 u = asu(f); u32 r = u + 0x7FFFu + ((u>>16)&1u); return (u16)(r>>16); }
__device__ __forceinline__ u32 pack2(float a, float b){ return (u32)f2bf(a) | (((u32)f2bf(b))<<16); }
__device__ __forceinline__ void bf8f(uint4 d, float* o){
  o[0]=asf(d.x<<16); o[1]=asf(d.x&0xFFFF0000u);
  o[2]=asf(d.y<<16); o[3]=asf(d.y&0xFFFF0000u);
  o[4]=asf(d.z<<16); o[5]=asf(d.z&0xFFFF0000u);
  o[6]=asf(d.w<<16); o[7]=asf(d.w&0xFFFF0000u);
}

// ---------------------------------------------------------------------------
// fp32 -> bf16 conversion (weights), 8 elems/thread
// ---------------------------------------------------------------------------
__global__ __launch_bounds__(256) void cvt_f32_bf16(
    const float* __restrict__ in, u16* __restrict__ out, int n)
{
  const int i = (blockIdx.x*256 + threadIdx.x)*8;
  if (i >= n) return;
  const float4 a = *(const float4*)(in + i);
  const float4 b = *(const float4*)(in + i + 4);
  uint4 st;
  st.x = pack2(a.x, a.y); st.y = pack2(a.z, a.w);
  st.z = pack2(b.x, b.y); st.w = pack2(b.z, b.w);
  *(uint4*)(out + i) = st;
}

// ---------------------------------------------------------------------------
// MFMA GEMM: C[M,N] = A[M,K] @ B[N,K]^T, bf16 in, fp32 accum.
// 128x128 tile, BK=32, 4 waves, each wave 64x64 (4x4 of 16x16x32 MFMA).
// ---------------------------------------------------------------------------
enum { EPI_NONE=0, EPI_BIAS_GELU=1, EPI_BIAS_RES=2 };

template<int EPI, typename OutT>
__global__ __launch_bounds__(256) void gemm_bt(
    const u16* __restrict__ A, const u16* __restrict__ B,
    const float* __restrict__ bias, const float* __restrict__ res,
    OutT* __restrict__ C, int M, int N, int K)
{
  __shared__ u16 As[128*32];
  __shared__ u16 Bs[128*32];
  const int tid  = threadIdx.x;
  const int wave = tid >> 6;
  const int lane = tid & 63;
  const int bm = blockIdx.y, bn = blockIdx.x;

  const int srow = wave*16 + (lane>>2);
  const int scol = (lane&3)*8;
  const u16* Ag = A + (size_t)bm*128*K;
  const u16* Bg = B + (size_t)bn*128*K;

  const int wm = (wave>>1)*64;
  const int wn = (wave&1)*64;
  const int fr = lane & 15;
  const int fk = (lane>>4)*8;

  floatx4 acc[4][4] = {};

  for (int k0 = 0; k0 < K; k0 += 32) {
    __syncthreads();
    #pragma unroll
    for (int t = 0; t < 2; ++t) {
      __builtin_amdgcn_global_load_lds(
          (__attribute__((address_space(1))) void*)(Ag + (t*64 + srow)*K + k0 + scol),
          (__attribute__((address_space(3))) void*)(As + (t*64 + wave*16)*32),
          16, 0, 0);
      __builtin_amdgcn_global_load_lds(
          (__attribute__((address_space(1))) void*)(Bg + (t*64 + srow)*K + k0 + scol),
          (__attribute__((address_space(3))) void*)(Bs + (t*64 + wave*16)*32),
          16, 0, 0);
    }
    __syncthreads();

    short8 af[4], bfr[4];
    #pragma unroll
    for (int i=0;i<4;i++) af[i]  = *(const short8*)(As + (wm + i*16 + fr)*32 + fk);
    #pragma unroll
    for (int j=0;j<4;j++) bfr[j] = *(const short8*)(Bs + (wn + j*16 + fr)*32 + fk);
    #pragma unroll
    for (int i=0;i<4;i++)
      #pragma unroll
      for (int j=0;j<4;j++)
        acc[i][j] = __builtin_amdgcn_mfma_f32_16x16x32_bf16(af[i], bfr[j], acc[i][j], 0, 0, 0);
  }

  const int col0 = bn*128 + wn + fr;
  float bv[4] = {0.f,0.f,0.f,0.f};
  if constexpr (EPI != EPI_NONE) {
    #pragma unroll
    for (int j=0;j<4;j++) bv[j] = bias[col0 + j*16];
  }
  const int rq = (lane>>4)*4;
  #pragma unroll
  for (int i=0;i<4;i++){
    #pragma unroll
    for (int rr=0;rr<4;rr++){
      const int m = bm*128 + wm + i*16 + rq + rr;
      const size_t rowoff = (size_t)m*N;
      #pragma unroll
      for (int j=0;j<4;j++){
        float vv = acc[i][j][rr];
        const int n = col0 + j*16;
        if constexpr (EPI == EPI_BIAS_GELU){
          vv += bv[j];
          vv = 0.5f*vv*(1.f + erff(vv*0.70710678118654752f));
        } else if constexpr (EPI == EPI_BIAS_RES){
          vv += bv[j] + res[rowoff + n];
        }
        if constexpr (sizeof(OutT) == 2) C[rowoff + n] = f2bf(vv);
        else                             C[rowoff + n] = vv;
      }
    }
  }
}

// ---------------------------------------------------------------------------
// LayerNorm over 512 (fp32 in, bf16 out), wave-per-row, 4 rows/block
// ---------------------------------------------------------------------------
__global__ __launch_bounds__(256) void ln512_kernel(
    const float* __restrict__ x, const float* __restrict__ w, const float* __restrict__ b,
    u16* __restrict__ out)
{
  const int row  = blockIdx.x*4 + (threadIdx.x>>6);
  const int lane = threadIdx.x & 63;
  const size_t base = (size_t)row*512 + lane*8;
  float v[8];
  { const float4 a = *(const float4*)(x + base);
    const float4 c = *(const float4*)(x + base + 4);
    v[0]=a.x; v[1]=a.y; v[2]=a.z; v[3]=a.w; v[4]=c.x; v[5]=c.y; v[6]=c.z; v[7]=c.w; }
  float s=0.f, sq=0.f;
  #pragma unroll
  for (int i=0;i<8;i++){ s += v[i]; sq += v[i]*v[i]; }
  for (int off=32; off>0; off>>=1){ s += __shfl_xor(s, off, 64); sq += __shfl_xor(sq, off, 64); }
  const float mu = s*(1.f/512.f);
  const float rs = rsqrtf(sq*(1.f/512.f) - mu*mu + 1e-5f);
  float o[8];
  #pragma unroll
  for (int i=0;i<8;i++)
    o[i] = (v[i]-mu)*rs*w[lane*8+i] + b[lane*8+i];
  uint4 st; st.x=pack2(o[0],o[1]); st.y=pack2(o[2],o[3]); st.z=pack2(o[4],o[5]); st.w=pack2(o[6],o[7]);
  *(uint4*)(out + base) = st;
}

// h = LN(ao)*w2+b2 + x (fp32 out) ; z = LN(h)*w3+b3 (bf16 out)
__global__ __launch_bounds__(256) void lnres_kernel(
    const u16* __restrict__ ao, const float* __restrict__ x,
    const float* __restrict__ w2, const float* __restrict__ b2,
    const float* __restrict__ w3, const float* __restrict__ b3,
    float* __restrict__ h, u16* __restrict__ z)
{
  const int row  = blockIdx.x*4 + (threadIdx.x>>6);
  const int lane = threadIdx.x & 63;
  const size_t base = (size_t)row*512 + lane*8;
  float a[8], xr[8];
  bf8f(*(const uint4*)(ao + base), a);
  { const float4 p = *(const float4*)(x + base);
    const float4 q = *(const float4*)(x + base + 4);
    xr[0]=p.x; xr[1]=p.y; xr[2]=p.z; xr[3]=p.w; xr[4]=q.x; xr[5]=q.y; xr[6]=q.z; xr[7]=q.w; }
  float s=0.f, sq=0.f;
  #pragma unroll
  for (int i=0;i<8;i++){ s += a[i]; sq += a[i]*a[i]; }
  for (int off=32; off>0; off>>=1){ s += __shfl_xor(s, off, 64); sq += __shfl_xor(sq, off, 64); }
  float mu = s*(1.f/512.f);
  float rs = rsqrtf(sq*(1.f/512.f) - mu*mu + 1e-5f);
  float hv[8];
  #pragma unroll
  for (int i=0;i<8;i++)
    hv[i] = (a[i]-mu)*rs*w2[lane*8+i] + b2[lane*8+i] + xr[i];
  { float4 p; p.x=hv[0]; p.y=hv[1]; p.z=hv[2]; p.w=hv[3];
    float4 q; q.x=hv[4]; q.y=hv[5]; q.z=hv[6]; q.w=hv[7];
    *(float4*)(h + base) = p; *(float4*)(h + base + 4) = q; }
  s=0.f; sq=0.f;
  #pragma unroll
  for (int i=0;i<8;i++){ s += hv[i]; sq += hv[i]*hv[i]; }
  for (int off=32; off>0; off>>=1){ s += __shfl_xor(s, off, 64); sq += __shfl_xor(sq, off, 64); }
  mu = s*(1.f/512.f);
  rs = rsqrtf(sq*(1.f/512.f) - mu*mu + 1e-5f);
  float zv[8];
  #pragma unroll
  for (int i=0;i<8;i++)
    zv[i] = (hv[i]-mu)*rs*w3[lane*8+i] + b3[lane*8+i];
  uint4 st; st.x=pack2(zv[0],zv[1]); st.y=pack2(zv[2],zv[3]); st.z=pack2(zv[4],zv[5]); st.w=pack2(zv[6],zv[7]);
  *(uint4*)(z + base) = st;
}

// LayerNorm over 2048 (bf16, in place safe)
__global__ __launch_bounds__(256) void ln2048_kernel(
    const u16* x, const float* __restrict__ w, const float* __restrict__ b,
    u16* out)
{
  const int row  = blockIdx.x*4 + (threadIdx.x>>6);
  const int lane = threadIdx.x & 63;
  const u16* xp = x + (size_t)row*2048;
  float v[32];
  #pragma unroll
  for (int g=0; g<4; ++g) bf8f(*(const uint4*)(xp + g*512 + lane*8), v + g*8);
  float s=0.f, sq=0.f;
  #pragma unroll
  for (int i=0;i<32;i++){ s += v[i]; sq += v[i]*v[i]; }
  for (int off=32; off>0; off>>=1){ s += __shfl_xor(s, off, 64); sq += __shfl_xor(sq, off, 64); }
  const float mu = s*(1.f/2048.f);
  const float rs = rsqrtf(sq*(1.f/2048.f) - mu*mu + 1e-5f);
  u16* op = out + (size_t)row*2048;
  #pragma unroll
  for (int g=0; g<4; ++g){
    float o[8];
    #pragma unroll
    for (int i=0;i<8;i++){
      const int idx = g*512 + lane*8 + i;
      o[i] = (v[g*8+i]-mu)*rs*w[idx] + b[idx];
    }
    uint4 st; st.x=pack2(o[0],o[1]); st.y=pack2(o[2],o[3]); st.z=pack2(o[4],o[5]); st.w=pack2(o[6],o[7]);
    *(uint4*)(op + g*512 + lane*8) = st;
  }
}

// ---------------------------------------------------------------------------
// V transpose: V[8192 tok][512] bf16 -> Vt[bh 64][dim 64][key 1024] bf16.
// Block = (bh, 64-key tile): coalesced read, padded-LDS transpose, coalesced
// write. 16 MB in + 16 MB out => ~8 us.
// ---------------------------------------------------------------------------
__global__ __launch_bounds__(256) void transpose_v(
    const u16* __restrict__ V, u16* __restrict__ Vt)
{
  __shared__ __align__(16) u16 T[64][72];   // pad 72 -> column reads spread banks
  const int bid = blockIdx.x;
  const int bh  = bid >> 4;     // 0..63
  const int kt  = bid & 15;     // 64-key tile
  const int b   = bh >> 3;
  const int h   = bh & 7;
  const int tid = threadIdx.x;

  // read: key = tid>>2, two 8-dim chunks at (tid&3)*16
  const int key = tid >> 2;
  const int dc  = (tid & 3) * 16;
  const u16* src = V + ((size_t)(b*1024 + kt*64 + key))*512 + h*64 + dc;
  const uint4 a0 = *(const uint4*)(src);
  const uint4 a1 = *(const uint4*)(src + 8);
  *(uint4*)(&T[key][dc])     = a0;
  *(uint4*)(&T[key][dc + 8]) = a1;
  __syncthreads();

  // write: dim row d = tid>>2, 16 keys at (tid&3)*16
  const int d  = tid >> 2;
  const int kc = (tid & 3) * 16;
  union { uint4 q[2]; u16 us[16]; } ow;
  #pragma unroll
  for (int i=0;i<16;i++) ow.us[i] = T[kc + i][d];
  u16* dst = Vt + ((size_t)(bh*64 + d))*1024 + kt*64 + kc;
  *(uint4*)(dst)     = ow.q[0];
  *(uint4*)(dst + 8) = ow.q[1];
}

// ---------------------------------------------------------------------------
// MFMA differential flash attention — R10.
// Block = 256 thr (4 waves) = one (b,h) x 64 Q rows; wave = 16 Q rows.
// K: double-buffered LDS via global_load_lds, staged for tile t+1 at the TOP
//    of tile t (T3-lite 2-phase; ONE barrier per tile, latency hidden under
//    QK+PV; zero registers held across compute -> no spills).
// V: NOT staged. PV B-frags read directly from global Vt[bh][dim][key]
//    (contiguous 16B/lane; per-head V = 128 KB, L1/L2 resident; lesson #7).
// P: rotated-slot LDS layout (conflict-free b16 writes, verified R9).
// Softmax denominators accumulate per-lane; ONE shuffle-reduce in epilogue.
// LDS = 36.9 KB -> 4 blocks/CU.
// ---------------------------------------------------------------------------
#define ATT_SCALE 0.17677669529663687f   // 32^-0.5

__global__ __launch_bounds__(256) void attn_mfma(
    const u16* __restrict__ Q, const u16* __restrict__ K, const u16* __restrict__ Vt,
    const float* __restrict__ lq1, const float* __restrict__ lk1,
    const float* __restrict__ lq2, const float* __restrict__ lk2,
    const float* __restrict__ subw, u16* __restrict__ out)
{
  __shared__ __align__(16) u16 Ks1[2][64*32];          // [buf][key][dim 0..31]
  __shared__ __align__(16) u16 Ks2[2][64*32];          // [buf][key][dim 32..63]
  __shared__ __align__(16) u16 PsBuf[2][2][4][16*40];  // [sub][khalf][wave][row*40]

  const int tid  = threadIdx.x;
  const int wave = tid >> 6;
  const int lane = tid & 63;
  const int quad = lane >> 4;
  const int l15  = lane & 15;

  const int bid = blockIdx.x;
  const int bh  = bid >> 4;
  const int qt  = bid & 15;
  const int b   = bh >> 3;
  const int h   = bh & 7;

  float t1 = 0.f, t2 = 0.f;
  for (int i=0;i<32;i++){ t1 += lq1[i]*lk1[i]; t2 += lq2[i]*lk2[i]; }
  const float lam = __expf(t1) - __expf(t2) + 0.2f;   // LAMBDA_INIT = 0.2

  // Q A-fragments: m = l15 (q row), k = quad*8..+8
  const int qrowg = b*1024 + qt*64 + wave*16 + l15;
  const short8 aq1 = *(const short8*)(Q + (size_t)qrowg*512 + 2*h*32 + quad*8);
  const short8 aq2 = *(const short8*)(Q + (size_t)qrowg*512 + 2*h*32 + 32 + quad*8);

  floatx4 O1[4] = {}, O2[4] = {};
  float l1acc[4] = {0.f,0.f,0.f,0.f};
  float l2acc[4] = {0.f,0.f,0.f,0.f};
  const floatx4 zf4 = {0.f,0.f,0.f,0.f};

  const int kvbase = b*1024;
  u16* p1w[2] = { &PsBuf[0][0][wave][0], &PsBuf[0][1][wave][0] };
  u16* p2w[2] = { &PsBuf[1][0][wave][0], &PsBuf[1][1][wave][0] };

  // K staging geometry (m97 pattern): wave w stages key rows w*16..+16
  const int srowK = wave*16 + (lane>>2);
  const int scolK = (lane&3)*8;
  const u16* Kbase = K + (size_t)(kvbase + srowK)*512 + 2*h*32 + scolK;

  // Vt per-lane base: dim row l15, key offset quad*8
  const u16* Vbase = Vt + ((size_t)bh*64 + l15)*1024 + quad*8;

  // prologue: stage tile 0 into buf 0
  {
    __builtin_amdgcn_global_load_lds(
        (__attribute__((address_space(1))) void*)(Kbase),
        (__attribute__((address_space(3))) void*)(&Ks1[0][wave*16*32]), 16, 0, 0);
    __builtin_amdgcn_global_load_lds(
        (__attribute__((address_space(1))) void*)(Kbase + 32),
        (__attribute__((address_space(3))) void*)(&Ks2[0][wave*16*32]), 16, 0, 0);
  }
  __syncthreads();   // drains vmcnt -> tile 0 visible

  const int pslotR = ((quad + (l15>>2)) & 3) * 8;      // PV A-frag read slot

  for (int t = 0; t < 16; ++t) {
    const int cur = t & 1;

    // ---- stage tile t+1 into the other buffer (async; drained at barrier)
    if (t < 15) {
      const u16* Kb = Kbase + (size_t)(t+1)*64*512;
      __builtin_amdgcn_global_load_lds(
          (__attribute__((address_space(1))) void*)(Kb),
          (__attribute__((address_space(3))) void*)(&Ks1[cur^1][wave*16*32]), 16, 0, 0);
      __builtin_amdgcn_global_load_lds(
          (__attribute__((address_space(1))) void*)(Kb + 32),
          (__attribute__((address_space(3))) void*)(&Ks2[cur^1][wave*16*32]), 16, 0, 0);
    }

    // ---- QK^T -> exp -> Ps (rotated slots); denominators per-lane
    #pragma unroll
    for (int kt=0; kt<4; ++kt){
      const short8 bk1 = *(const short8*)(&Ks1[cur][(kt*16 + l15)*32 + quad*8]);
      const short8 bk2 = *(const short8*)(&Ks2[cur][(kt*16 + l15)*32 + quad*8]);
      const floatx4 s1 = __builtin_amdgcn_mfma_f32_16x16x32_bf16(aq1, bk1, zf4, 0, 0, 0);
      const floatx4 s2 = __builtin_amdgcn_mfma_f32_16x16x32_bf16(aq2, bk2, zf4, 0, 0, 0);
      const int wslot = (((kt&1)*2 + (l15>>3) + quad) & 3) * 8;
      u16* d1 = p1w[kt>>1] + wslot + (l15&7);
      u16* d2 = p2w[kt>>1] + wslot + (l15&7);
      #pragma unroll
      for (int rr=0; rr<4; ++rr){
        const float p1 = __expf(s1[rr]*ATT_SCALE);
        const float p2 = __expf(s2[rr]*ATT_SCALE);
        d1[(quad*4+rr)*40] = f2bf(p1);
        d2[(quad*4+rr)*40] = f2bf(p2);
        l1acc[rr] += p1;
        l2acc[rr] += p2;
      }
    }

    // ---- PV: A = P from LDS (wave-local RAW), B = Vt direct from global
    short8 ap1[2], ap2[2];
    ap1[0] = *(const short8*)(p1w[0] + l15*40 + pslotR);
    ap1[1] = *(const short8*)(p1w[1] + l15*40 + pslotR);
    ap2[0] = *(const short8*)(p2w[0] + l15*40 + pslotR);
    ap2[1] = *(const short8*)(p2w[1] + l15*40 + pslotR);
    const u16* Vb = Vbase + t*64;
    #pragma unroll
    for (int nt=0; nt<4; ++nt){
      const short8 bv0 = *(const short8*)(Vb + (size_t)nt*16*1024);
      const short8 bv1 = *(const short8*)(Vb + (size_t)nt*16*1024 + 32);
      O1[nt] = __builtin_amdgcn_mfma_f32_16x16x32_bf16(ap1[0], bv0, O1[nt], 0, 0, 0);
      O1[nt] = __builtin_amdgcn_mfma_f32_16x16x32_bf16(ap1[1], bv1, O1[nt], 0, 0, 0);
      O2[nt] = __builtin_amdgcn_mfma_f32_16x16x32_bf16(ap2[0], bv0, O2[nt], 0, 0, 0);
      O2[nt] = __builtin_amdgcn_mfma_f32_16x16x32_bf16(ap2[1], bv1, O2[nt], 0, 0, 0);
    }

    // ---- single barrier: staging for t+1 done (vmcnt drain) + all waves
    //      finished reading buf[cur]
    if (t < 15) __syncthreads();
  }

  // deferred softmax-denominator reduce over the 16 key-lanes (once)
  #pragma unroll
  for (int rr=0; rr<4; ++rr){
    float v1 = l1acc[rr], v2 = l2acc[rr];
    v1 += __shfl_xor(v1, 1, 64); v2 += __shfl_xor(v2, 1, 64);
    v1 += __shfl_xor(v1, 2, 64); v2 += __shfl_xor(v2, 2, 64);
    v1 += __shfl_xor(v1, 4, 64); v2 += __shfl_xor(v2, 4, 64);
    v1 += __shfl_xor(v1, 8, 64); v2 += __shfl_xor(v2, 8, 64);
    l1acc[rr] = v1; l2acc[rr] = v2;
  }

  // --- epilogue: combine, rmsnorm over 64 dims, *0.8, store bf16
  float sw[4];
  #pragma unroll
  for (int nt=0; nt<4; ++nt) sw[nt] = subw[nt*16 + l15];

  #pragma unroll
  for (int rr=0; rr<4; ++rr){
    const int row = quad*4 + rr;
    const float il1 = 1.f / l1acc[rr];
    const float cl2 = lam / l2acc[rr];
    float o[4]; float ss = 0.f;
    #pragma unroll
    for (int nt=0; nt<4; ++nt){
      o[nt] = O1[nt][rr]*il1 - O2[nt][rr]*cl2;
      ss += o[nt]*o[nt];
    }
    ss += __shfl_xor(ss, 1, 64);
    ss += __shfl_xor(ss, 2, 64);
    ss += __shfl_xor(ss, 4, 64);
    ss += __shfl_xor(ss, 8, 64);
    const float rs = rsqrtf(ss*(1.f/64.f) + 1e-5f) * 0.8f;
    const int orow = b*1024 + qt*64 + wave*16 + row;
    u16* op = out + (size_t)orow*512 + h*64 + l15;
    #pragma unroll
    for (int nt=0; nt<4; ++nt)
      op[nt*16] = f2bf(o[nt]*rs*sw[nt]);
  }
}

// ---------------------------------------------------------------------------
extern "C" void kernel_launch(void* const* d_in, const int* in_sizes, int n_in,
                              void* d_out, int out_size, void* d_ws, size_t ws_size,
                              hipStream_t stream)
{
  (void)in_sizes; (void)n_in; (void)out_size; (void)ws_size;
  const float* x    = (const float*)d_in[0];
  const float* Wq   = (const float*)d_in[1];
  const float* Wk   = (const float*)d_in[2];
  const float* Wv   = (const float*)d_in[3];
  const float* Wo   = (const float*)d_in[4];
  const float* lq1  = (const float*)d_in[5];
  const float* lk1  = (const float*)d_in[6];
  const float* lq2  = (const float*)d_in[7];
  const float* lk2  = (const float*)d_in[8];
  const float* subw = (const float*)d_in[9];
  const float* n1w  = (const float*)d_in[10];
  const float* n1b  = (const float*)d_in[11];
  const float* n2w  = (const float*)d_in[12];
  const float* n2b  = (const float*)d_in[13];
  const float* m1w  = (const float*)d_in[14];
  const float* m1b  = (const float*)d_in[15];
  const float* mW1  = (const float*)d_in[16];
  const float* mb1  = (const float*)d_in[17];
  const float* m2w  = (const float*)d_in[18];
  const float* m2b  = (const float*)d_in[19];
  const float* mW2  = (const float*)d_in[20];
  const float* mb2  = (const float*)d_in[21];
  float* out = (float*)d_out;   // fp32 output

  char* ws = (char*)d_ws;
  const size_t MB = (size_t)1 << 20;
  u16*  xn  = (u16*)(ws + 0*MB);
  u16*  q   = (u16*)(ws + 8*MB);
  u16*  k   = (u16*)(ws + 16*MB);
  u16*  v   = (u16*)(ws + 24*MB);
  u16*  a   = (u16*)(ws + 0*MB);    // reuse xn
  u16*  ao  = (u16*)(ws + 8*MB);    // reuse q
  u16*  z1  = (u16*)(ws + 16*MB);   // reuse k
  float* h  = (float*)(ws + 32*MB);
  u16*  vt  = (u16*)(ws + 32*MB);   // Vt[64][64][1024]; dead before h is written
  u16*  t   = (u16*)(ws + 48*MB);   // [48,80), LN2048 in place
  u16* Wqb  = (u16*)(ws + 80*MB);
  u16* Wkb  = (u16*)(ws + 80*MB + 512*1024);
  u16* Wvb  = (u16*)(ws + 81*MB);
  u16* Wob  = (u16*)(ws + 81*MB + 512*1024);
  u16* W1b  = (u16*)(ws + 82*MB);
  u16* W2b  = (u16*)(ws + 84*MB);

  const int M = 8192;

  cvt_f32_bf16<<<128, 256, 0, stream>>>(Wq, Wqb, 512*512);
  cvt_f32_bf16<<<128, 256, 0, stream>>>(Wk, Wkb, 512*512);
  cvt_f32_bf16<<<128, 256, 0, stream>>>(Wv, Wvb, 512*512);
  cvt_f32_bf16<<<128, 256, 0, stream>>>(Wo, Wob, 512*512);
  cvt_f32_bf16<<<512, 256, 0, stream>>>(mW1, W1b, 2048*512);
  cvt_f32_bf16<<<512, 256, 0, stream>>>(mW2, W2b, 2048*512);

  ln512_kernel<<<2048, 256, 0, stream>>>(x, n1w, n1b, xn);

  gemm_bt<EPI_NONE,u16><<<dim3(4,64), 256, 0, stream>>>(xn, Wqb, nullptr, nullptr, q, M, 512, 512);
  gemm_bt<EPI_NONE,u16><<<dim3(4,64), 256, 0, stream>>>(xn, Wkb, nullptr, nullptr, k, M, 512, 512);
  gemm_bt<EPI_NONE,u16><<<dim3(4,64), 256, 0, stream>>>(xn, Wvb, nullptr, nullptr, v, M, 512, 512);

  transpose_v<<<1024, 256, 0, stream>>>(v, vt);

  attn_mfma<<<1024, 256, 0, stream>>>(q, k, vt, lq1, lk1, lq2, lk2, subw, a);

  gemm_bt<EPI_NONE,u16><<<dim3(4,64), 256, 0, stream>>>(a, Wob, nullptr, nullptr, ao, M, 512, 512);

  lnres_kernel<<<2048, 256, 0, stream>>>(ao, x, n2w, n2b, m1w, m1b, h, z1);

  gemm_bt<EPI_BIAS_GELU,u16><<<dim3(16,64), 256, 0, stream>>>(z1, W1b, mb1, nullptr, t, M, 2048, 512);

  ln2048_kernel<<<2048, 256, 0, stream>>>(t, m2w, m2b, t);

  gemm_bt<EPI_BIAS_RES,float><<<dim3(4,64), 256, 0, stream>>>(t, W2b, mb2, h, out, M, 512, 2048);
}

// Round 3
// 371.139 us; speedup vs baseline: 1.1570x; 1.1570x over previous
//
#include <hip/hip_runtime.h>
#include <cstdint>
#include <cstddef>

typedef unsigned short u16;
typedef unsigned int   u32;
typedef __attribute__((ext_vector_type(8))) short short8;
typedef __attribute__((ext_vector_type(4))) float floatx4;

__device__ __forceinline__ float asf(u32 u){ union{u32 u; float f;} v; v.u=u; return v.f; }
__device__ __forceinline__ u32 asu(float f){ union{float f; u32 u;} v; v.f=f; return v.u; }
__device__ __forceinline__ float bf2f(u16 u){ return asf(((u32)u)<<16); }
__device__ __forceinline__ u16 f2bf(float f){ u32 u = asu(f); u32 r = u + 0x7FFFu + ((u>>16)&1u); return (u16)(r>>16); }
__device__ __forceinline__ u32 pack2(float a, float b){ return (u32)f2bf(a) | (((u32)f2bf(b))<<16); }
__device__ __forceinline__ void bf8f(uint4 d, float* o){
  o[0]=asf(d.x<<16); o[1]=asf(d.x&0xFFFF0000u);
  o[2]=asf(d.y<<16); o[3]=asf(d.y&0xFFFF0000u);
  o[4]=asf(d.z<<16); o[5]=asf(d.z&0xFFFF0000u);
  o[6]=asf(d.w<<16); o[7]=asf(d.w&0xFFFF0000u);
}

// ---------------------------------------------------------------------------
// fp32 -> bf16 conversion (weights), 8 elems/thread
// ---------------------------------------------------------------------------
__global__ __launch_bounds__(256) void cvt_f32_bf16(
    const float* __restrict__ in, u16* __restrict__ out, int n)
{
  const int i = (blockIdx.x*256 + threadIdx.x)*8;
  if (i >= n) return;
  const float4 a = *(const float4*)(in + i);
  const float4 b = *(const float4*)(in + i + 4);
  uint4 st;
  st.x = pack2(a.x, a.y); st.y = pack2(a.z, a.w);
  st.z = pack2(b.x, b.y); st.w = pack2(b.z, b.w);
  *(uint4*)(out + i) = st;
}

// ---------------------------------------------------------------------------
// MFMA GEMM: C[M,N] = A[M,K] @ B[N,K]^T, bf16 in, fp32 accum.
// 128x128 tile, BK=32, 4 waves, each wave 64x64 (4x4 of 16x16x32 MFMA).
// ---------------------------------------------------------------------------
enum { EPI_NONE=0, EPI_BIAS_GELU=1, EPI_BIAS_RES=2 };

template<int EPI, typename OutT>
__global__ __launch_bounds__(256) void gemm_bt(
    const u16* __restrict__ A, const u16* __restrict__ B,
    const float* __restrict__ bias, const float* __restrict__ res,
    OutT* __restrict__ C, int M, int N, int K)
{
  __shared__ u16 As[128*32];
  __shared__ u16 Bs[128*32];
  const int tid  = threadIdx.x;
  const int wave = tid >> 6;
  const int lane = tid & 63;
  const int bm = blockIdx.y, bn = blockIdx.x;

  const int srow = wave*16 + (lane>>2);
  const int scol = (lane&3)*8;
  const u16* Ag = A + (size_t)bm*128*K;
  const u16* Bg = B + (size_t)bn*128*K;

  const int wm = (wave>>1)*64;
  const int wn = (wave&1)*64;
  const int fr = lane & 15;
  const int fk = (lane>>4)*8;

  floatx4 acc[4][4] = {};

  for (int k0 = 0; k0 < K; k0 += 32) {
    __syncthreads();
    #pragma unroll
    for (int t = 0; t < 2; ++t) {
      __builtin_amdgcn_global_load_lds(
          (__attribute__((address_space(1))) void*)(Ag + (t*64 + srow)*K + k0 + scol),
          (__attribute__((address_space(3))) void*)(As + (t*64 + wave*16)*32),
          16, 0, 0);
      __builtin_amdgcn_global_load_lds(
          (__attribute__((address_space(1))) void*)(Bg + (t*64 + srow)*K + k0 + scol),
          (__attribute__((address_space(3))) void*)(Bs + (t*64 + wave*16)*32),
          16, 0, 0);
    }
    __syncthreads();

    short8 af[4], bfr[4];
    #pragma unroll
    for (int i=0;i<4;i++) af[i]  = *(const short8*)(As + (wm + i*16 + fr)*32 + fk);
    #pragma unroll
    for (int j=0;j<4;j++) bfr[j] = *(const short8*)(Bs + (wn + j*16 + fr)*32 + fk);
    #pragma unroll
    for (int i=0;i<4;i++)
      #pragma unroll
      for (int j=0;j<4;j++)
        acc[i][j] = __builtin_amdgcn_mfma_f32_16x16x32_bf16(af[i], bfr[j], acc[i][j], 0, 0, 0);
  }

  const int col0 = bn*128 + wn + fr;
  float bv[4] = {0.f,0.f,0.f,0.f};
  if constexpr (EPI != EPI_NONE) {
    #pragma unroll
    for (int j=0;j<4;j++) bv[j] = bias[col0 + j*16];
  }
  const int rq = (lane>>4)*4;
  #pragma unroll
  for (int i=0;i<4;i++){
    #pragma unroll
    for (int rr=0;rr<4;rr++){
      const int m = bm*128 + wm + i*16 + rq + rr;
      const size_t rowoff = (size_t)m*N;
      #pragma unroll
      for (int j=0;j<4;j++){
        float vv = acc[i][j][rr];
        const int n = col0 + j*16;
        if constexpr (EPI == EPI_BIAS_GELU){
          vv += bv[j];
          vv = 0.5f*vv*(1.f + erff(vv*0.70710678118654752f));
        } else if constexpr (EPI == EPI_BIAS_RES){
          vv += bv[j] + res[rowoff + n];
        }
        if constexpr (sizeof(OutT) == 2) C[rowoff + n] = f2bf(vv);
        else                             C[rowoff + n] = vv;
      }
    }
  }
}

// ---------------------------------------------------------------------------
// LayerNorm over 512 (fp32 in, bf16 out), wave-per-row, 4 rows/block
// ---------------------------------------------------------------------------
__global__ __launch_bounds__(256) void ln512_kernel(
    const float* __restrict__ x, const float* __restrict__ w, const float* __restrict__ b,
    u16* __restrict__ out)
{
  const int row  = blockIdx.x*4 + (threadIdx.x>>6);
  const int lane = threadIdx.x & 63;
  const size_t base = (size_t)row*512 + lane*8;
  float v[8];
  { const float4 a = *(const float4*)(x + base);
    const float4 c = *(const float4*)(x + base + 4);
    v[0]=a.x; v[1]=a.y; v[2]=a.z; v[3]=a.w; v[4]=c.x; v[5]=c.y; v[6]=c.z; v[7]=c.w; }
  float s=0.f, sq=0.f;
  #pragma unroll
  for (int i=0;i<8;i++){ s += v[i]; sq += v[i]*v[i]; }
  for (int off=32; off>0; off>>=1){ s += __shfl_xor(s, off, 64); sq += __shfl_xor(sq, off, 64); }
  const float mu = s*(1.f/512.f);
  const float rs = rsqrtf(sq*(1.f/512.f) - mu*mu + 1e-5f);
  float o[8];
  #pragma unroll
  for (int i=0;i<8;i++)
    o[i] = (v[i]-mu)*rs*w[lane*8+i] + b[lane*8+i];
  uint4 st; st.x=pack2(o[0],o[1]); st.y=pack2(o[2],o[3]); st.z=pack2(o[4],o[5]); st.w=pack2(o[6],o[7]);
  *(uint4*)(out + base) = st;
}

// h = LN(ao)*w2+b2 + x (fp32 out) ; z = LN(h)*w3+b3 (bf16 out)
__global__ __launch_bounds__(256) void lnres_kernel(
    const u16* __restrict__ ao, const float* __restrict__ x,
    const float* __restrict__ w2, const float* __restrict__ b2,
    const float* __restrict__ w3, const float* __restrict__ b3,
    float* __restrict__ h, u16* __restrict__ z)
{
  const int row  = blockIdx.x*4 + (threadIdx.x>>6);
  const int lane = threadIdx.x & 63;
  const size_t base = (size_t)row*512 + lane*8;
  float a[8], xr[8];
  bf8f(*(const uint4*)(ao + base), a);
  { const float4 p = *(const float4*)(x + base);
    const float4 q = *(const float4*)(x + base + 4);
    xr[0]=p.x; xr[1]=p.y; xr[2]=p.z; xr[3]=p.w; xr[4]=q.x; xr[5]=q.y; xr[6]=q.z; xr[7]=q.w; }
  float s=0.f, sq=0.f;
  #pragma unroll
  for (int i=0;i<8;i++){ s += a[i]; sq += a[i]*a[i]; }
  for (int off=32; off>0; off>>=1){ s += __shfl_xor(s, off, 64); sq += __shfl_xor(sq, off, 64); }
  float mu = s*(1.f/512.f);
  float rs = rsqrtf(sq*(1.f/512.f) - mu*mu + 1e-5f);
  float hv[8];
  #pragma unroll
  for (int i=0;i<8;i++)
    hv[i] = (a[i]-mu)*rs*w2[lane*8+i] + b2[lane*8+i] + xr[i];
  { float4 p; p.x=hv[0]; p.y=hv[1]; p.z=hv[2]; p.w=hv[3];
    float4 q; q.x=hv[4]; q.y=hv[5]; q.z=hv[6]; q.w=hv[7];
    *(float4*)(h + base) = p; *(float4*)(h + base + 4) = q; }
  s=0.f; sq=0.f;
  #pragma unroll
  for (int i=0;i<8;i++){ s += hv[i]; sq += hv[i]*hv[i]; }
  for (int off=32; off>0; off>>=1){ s += __shfl_xor(s, off, 64); sq += __shfl_xor(sq, off, 64); }
  mu = s*(1.f/512.f);
  rs = rsqrtf(sq*(1.f/512.f) - mu*mu + 1e-5f);
  float zv[8];
  #pragma unroll
  for (int i=0;i<8;i++)
    zv[i] = (hv[i]-mu)*rs*w3[lane*8+i] + b3[lane*8+i];
  uint4 st; st.x=pack2(zv[0],zv[1]); st.y=pack2(zv[2],zv[3]); st.z=pack2(zv[4],zv[5]); st.w=pack2(zv[6],zv[7]);
  *(uint4*)(z + base) = st;
}

// LayerNorm over 2048 (bf16, in place safe)
__global__ __launch_bounds__(256) void ln2048_kernel(
    const u16* x, const float* __restrict__ w, const float* __restrict__ b,
    u16* out)
{
  const int row  = blockIdx.x*4 + (threadIdx.x>>6);
  const int lane = threadIdx.x & 63;
  const u16* xp = x + (size_t)row*2048;
  float v[32];
  #pragma unroll
  for (int g=0; g<4; ++g) bf8f(*(const uint4*)(xp + g*512 + lane*8), v + g*8);
  float s=0.f, sq=0.f;
  #pragma unroll
  for (int i=0;i<32;i++){ s += v[i]; sq += v[i]*v[i]; }
  for (int off=32; off>0; off>>=1){ s += __shfl_xor(s, off, 64); sq += __shfl_xor(sq, off, 64); }
  const float mu = s*(1.f/2048.f);
  const float rs = rsqrtf(sq*(1.f/2048.f) - mu*mu + 1e-5f);
  u16* op = out + (size_t)row*2048;
  #pragma unroll
  for (int g=0; g<4; ++g){
    float o[8];
    #pragma unroll
    for (int i=0;i<8;i++){
      const int idx = g*512 + lane*8 + i;
      o[i] = (v[g*8+i]-mu)*rs*w[idx] + b[idx];
    }
    uint4 st; st.x=pack2(o[0],o[1]); st.y=pack2(o[2],o[3]); st.z=pack2(o[4],o[5]); st.w=pack2(o[6],o[7]);
    *(uint4*)(op + g*512 + lane*8) = st;
  }
}

// ---------------------------------------------------------------------------
// V transpose: V[8192 tok][512] bf16 -> Vt[bh 64][dim 64][key 1024] bf16.
// ---------------------------------------------------------------------------
__global__ __launch_bounds__(256) void transpose_v(
    const u16* __restrict__ V, u16* __restrict__ Vt)
{
  __shared__ __align__(16) u16 T[64][72];   // pad 72 -> column reads spread banks
  const int bid = blockIdx.x;
  const int bh  = bid >> 4;     // 0..63
  const int kt  = bid & 15;     // 64-key tile
  const int b   = bh >> 3;
  const int h   = bh & 7;
  const int tid = threadIdx.x;

  const int key = tid >> 2;
  const int dc  = (tid & 3) * 16;
  const u16* src = V + ((size_t)(b*1024 + kt*64 + key))*512 + h*64 + dc;
  const uint4 a0 = *(const uint4*)(src);
  const uint4 a1 = *(const uint4*)(src + 8);
  *(uint4*)(&T[key][dc])     = a0;
  *(uint4*)(&T[key][dc + 8]) = a1;
  __syncthreads();

  const int d  = tid >> 2;
  const int kc = (tid & 3) * 16;
  union { uint4 q[2]; u16 us[16]; } ow;
  #pragma unroll
  for (int i=0;i<16;i++) ow.us[i] = T[kc + i][d];
  u16* dst = Vt + ((size_t)(bh*64 + d))*1024 + kt*64 + kc;
  *(uint4*)(dst)     = ow.q[0];
  *(uint4*)(dst + 8) = ow.q[1];
}

// ---------------------------------------------------------------------------
// MFMA differential flash attention — R11.
// Block = 256 thr (4 waves) = one (b,h) x 64 Q rows; wave = 16 Q rows.
// K AND V (pre-transposed Vt) double-buffered in LDS via global_load_lds,
// staged for tile t+1 at the top of tile t; ONE barrier per tile.
// Conflict-free LDS reads via XOR swizzle applied on BOTH sides (rule 21):
// linear LDS dest + XOR-pre-swizzled GLOBAL source + XOR'd read offsets.
//   K  rows 64B  (4 slots): chunk ^= (row>>1)&3
//   Vt rows 128B (8 slots): chunk ^= row&7
// P: one khalf at a time (stride-32 rotated slots, wave-local), 8 KB.
// LDS = 16 + 16 + 8 = 40 KB -> 4 blocks/CU.
// Softmax denominators accumulate per-lane; ONE shuffle-reduce in epilogue.
// ---------------------------------------------------------------------------
#define ATT_SCALE 0.17677669529663687f   // 32^-0.5

__global__ __launch_bounds__(256) void attn_mfma(
    const u16* __restrict__ Q, const u16* __restrict__ K, const u16* __restrict__ Vt,
    const float* __restrict__ lq1, const float* __restrict__ lk1,
    const float* __restrict__ lq2, const float* __restrict__ lk2,
    const float* __restrict__ subw, u16* __restrict__ out)
{
  __shared__ __align__(16) u16 Ks1[2][64*32];   // [buf][key][dim 0..31]  8 KB
  __shared__ __align__(16) u16 Ks2[2][64*32];   // [buf][key][dim 32..63] 8 KB
  __shared__ __align__(16) u16 Vs [2][64*64];   // [buf][dim][key 0..63] 16 KB
  __shared__ __align__(16) u16 Ps [2][4][16*32];// [sub][wave][row*32]    8 KB

  const int tid  = threadIdx.x;
  const int wave = tid >> 6;
  const int lane = tid & 63;
  const int quad = lane >> 4;
  const int l15  = lane & 15;

  const int bid = blockIdx.x;
  const int bh  = bid >> 4;
  const int qt  = bid & 15;
  const int b   = bh >> 3;
  const int h   = bh & 7;

  float t1 = 0.f, t2 = 0.f;
  for (int i=0;i<32;i++){ t1 += lq1[i]*lk1[i]; t2 += lq2[i]*lk2[i]; }
  const float lam = __expf(t1) - __expf(t2) + 0.2f;   // LAMBDA_INIT = 0.2

  // Q A-fragments: m = l15 (q row), k = quad*8..+8
  const int qrowg = b*1024 + qt*64 + wave*16 + l15;
  const short8 aq1 = *(const short8*)(Q + (size_t)qrowg*512 + 2*h*32 + quad*8);
  const short8 aq2 = *(const short8*)(Q + (size_t)qrowg*512 + 2*h*32 + 32 + quad*8);

  floatx4 O1[4] = {}, O2[4] = {};
  float l1acc[4] = {0.f,0.f,0.f,0.f};
  float l2acc[4] = {0.f,0.f,0.f,0.f};
  const floatx4 zf4 = {0.f,0.f,0.f,0.f};

  const int kvbase = b*1024;
  u16* pw1 = &Ps[0][wave][0];
  u16* pw2 = &Ps[1][wave][0];

  // --- staging geometry ---
  // K: lane -> LDS row wave*16+(lane>>2), slot lane&3; source chunk XOR'd.
  const int kchunk = ((lane&3) ^ ((lane>>3)&3)) * 8;     // swizzled 8-dim chunk
  const u16* KbaseS = K + (size_t)(kvbase + wave*16 + (lane>>2))*512 + 2*h*32 + kchunk;
  // V: op o stages LDS rows wave*16+o*8+(lane>>3), slot lane&7; source XOR'd.
  const int vchunk = ((lane&7) ^ (lane>>3)) * 8;         // swizzled 8-key chunk
  const u16* VbaseS = Vt + ((size_t)bh*64 + wave*16 + (lane>>3))*1024 + vchunk;

  #define STAGE_TILE(buf, tt)                                                     \
    do {                                                                          \
      const u16* kp = KbaseS + (size_t)(tt)*64*512;                               \
      __builtin_amdgcn_global_load_lds(                                           \
          (__attribute__((address_space(1))) void*)(kp),                          \
          (__attribute__((address_space(3))) void*)(&Ks1[buf][wave*16*32]), 16, 0, 0); \
      __builtin_amdgcn_global_load_lds(                                           \
          (__attribute__((address_space(1))) void*)(kp + 32),                     \
          (__attribute__((address_space(3))) void*)(&Ks2[buf][wave*16*32]), 16, 0, 0); \
      const u16* vp = VbaseS + (tt)*64;                                           \
      __builtin_amdgcn_global_load_lds(                                           \
          (__attribute__((address_space(1))) void*)(vp),                          \
          (__attribute__((address_space(3))) void*)(&Vs[buf][wave*16*64]), 16, 0, 0); \
      __builtin_amdgcn_global_load_lds(                                           \
          (__attribute__((address_space(1))) void*)(vp + (size_t)8*1024),         \
          (__attribute__((address_space(3))) void*)(&Vs[buf][(wave*16+8)*64]), 16, 0, 0); \
    } while (0)

  // prologue: stage tile 0 into buf 0
  STAGE_TILE(0, 0);
  __syncthreads();   // vmcnt drain -> tile 0 visible

  // read-side swizzled offsets
  const int kslotR = (quad ^ ((l15>>1)&3)) * 8;          // K B-frag slot
  const int pslotR = ((quad + (l15>>2)) & 3) * 8;        // P A-frag slot (rotate)

  for (int t = 0; t < 16; ++t) {
    const int cur = t & 1;

    // ---- stage tile t+1 into the other buffer (async; drained at barrier)
    if (t < 15) STAGE_TILE(cur^1, t+1);

    // ---- two khalves, sequential (Ps shared; wave-local in-order DS ops)
    #pragma unroll
    for (int kh = 0; kh < 2; ++kh) {
      // QK^T -> exp -> Ps (rotated slots); denominators per-lane
      #pragma unroll
      for (int ktl = 0; ktl < 2; ++ktl) {
        const int kt = kh*2 + ktl;
        const short8 bk1 = *(const short8*)(&Ks1[cur][(kt*16 + l15)*32 + kslotR]);
        const short8 bk2 = *(const short8*)(&Ks2[cur][(kt*16 + l15)*32 + kslotR]);
        const floatx4 s1 = __builtin_amdgcn_mfma_f32_16x16x32_bf16(aq1, bk1, zf4, 0, 0, 0);
        const floatx4 s2 = __builtin_amdgcn_mfma_f32_16x16x32_bf16(aq2, bk2, zf4, 0, 0, 0);
        const int wslot = ((ktl*2 + (l15>>3) + quad) & 3)*8;
        u16* d1 = pw1 + wslot + (l15&7);
        u16* d2 = pw2 + wslot + (l15&7);
        #pragma unroll
        for (int rr = 0; rr < 4; ++rr) {
          const float p1 = __expf(s1[rr]*ATT_SCALE);
          const float p2 = __expf(s2[rr]*ATT_SCALE);
          d1[(quad*4+rr)*32] = f2bf(p1);
          d2[(quad*4+rr)*32] = f2bf(p2);
          l1acc[rr] += p1;
          l2acc[rr] += p2;
        }
      }
      // P A-frags (wave-local RAW; compiler inserts lgkm waits)
      const short8 ap1 = *(const short8*)(pw1 + l15*32 + pslotR);
      const short8 ap2 = *(const short8*)(pw2 + l15*32 + pslotR);
      // PV: B = Vs, swizzled slot (kh*4+quad) ^ (l15&7)
      const int vslotR = ((kh*4 + quad) ^ (l15&7)) * 8;
      #pragma unroll
      for (int nt = 0; nt < 4; ++nt) {
        const short8 bv = *(const short8*)(&Vs[cur][(nt*16 + l15)*64 + vslotR]);
        O1[nt] = __builtin_amdgcn_mfma_f32_16x16x32_bf16(ap1, bv, O1[nt], 0, 0, 0);
        O2[nt] = __builtin_amdgcn_mfma_f32_16x16x32_bf16(ap2, bv, O2[nt], 0, 0, 0);
      }
    }

    // ---- single barrier: staging for t+1 complete (vmcnt drain) + all waves
    //      done reading buf[cur] before it is overwritten at iteration t+1
    if (t < 15) __syncthreads();
  }
  #undef STAGE_TILE

  // deferred softmax-denominator reduce over the 16 key-lanes (once)
  #pragma unroll
  for (int rr=0; rr<4; ++rr){
    float v1 = l1acc[rr], v2 = l2acc[rr];
    v1 += __shfl_xor(v1, 1, 64); v2 += __shfl_xor(v2, 1, 64);
    v1 += __shfl_xor(v1, 2, 64); v2 += __shfl_xor(v2, 2, 64);
    v1 += __shfl_xor(v1, 4, 64); v2 += __shfl_xor(v2, 4, 64);
    v1 += __shfl_xor(v1, 8, 64); v2 += __shfl_xor(v2, 8, 64);
    l1acc[rr] = v1; l2acc[rr] = v2;
  }

  // --- epilogue: combine, rmsnorm over 64 dims, *0.8, store bf16
  float sw[4];
  #pragma unroll
  for (int nt=0; nt<4; ++nt) sw[nt] = subw[nt*16 + l15];

  #pragma unroll
  for (int rr=0; rr<4; ++rr){
    const int row = quad*4 + rr;
    const float il1 = 1.f / l1acc[rr];
    const float cl2 = lam / l2acc[rr];
    float o[4]; float ss = 0.f;
    #pragma unroll
    for (int nt=0; nt<4; ++nt){
      o[nt] = O1[nt][rr]*il1 - O2[nt][rr]*cl2;
      ss += o[nt]*o[nt];
    }
    ss += __shfl_xor(ss, 1, 64);
    ss += __shfl_xor(ss, 2, 64);
    ss += __shfl_xor(ss, 4, 64);
    ss += __shfl_xor(ss, 8, 64);
    const float rs = rsqrtf(ss*(1.f/64.f) + 1e-5f) * 0.8f;
    const int orow = b*1024 + qt*64 + wave*16 + row;
    u16* op = out + (size_t)orow*512 + h*64 + l15;
    #pragma unroll
    for (int nt=0; nt<4; ++nt)
      op[nt*16] = f2bf(o[nt]*rs*sw[nt]);
  }
}

// ---------------------------------------------------------------------------
extern "C" void kernel_launch(void* const* d_in, const int* in_sizes, int n_in,
                              void* d_out, int out_size, void* d_ws, size_t ws_size,
                              hipStream_t stream)
{
  (void)in_sizes; (void)n_in; (void)out_size; (void)ws_size;
  const float* x    = (const float*)d_in[0];
  const float* Wq   = (const float*)d_in[1];
  const float* Wk   = (const float*)d_in[2];
  const float* Wv   = (const float*)d_in[3];
  const float* Wo   = (const float*)d_in[4];
  const float* lq1  = (const float*)d_in[5];
  const float* lk1  = (const float*)d_in[6];
  const float* lq2  = (const float*)d_in[7];
  const float* lk2  = (const float*)d_in[8];
  const float* subw = (const float*)d_in[9];
  const float* n1w  = (const float*)d_in[10];
  const float* n1b  = (const float*)d_in[11];
  const float* n2w  = (const float*)d_in[12];
  const float* n2b  = (const float*)d_in[13];
  const float* m1w  = (const float*)d_in[14];
  const float* m1b  = (const float*)d_in[15];
  const float* mW1  = (const float*)d_in[16];
  const float* mb1  = (const float*)d_in[17];
  const float* m2w  = (const float*)d_in[18];
  const float* m2b  = (const float*)d_in[19];
  const float* mW2  = (const float*)d_in[20];
  const float* mb2  = (const float*)d_in[21];
  float* out = (float*)d_out;   // fp32 output

  char* ws = (char*)d_ws;
  const size_t MB = (size_t)1 << 20;
  u16*  xn  = (u16*)(ws + 0*MB);
  u16*  q   = (u16*)(ws + 8*MB);
  u16*  k   = (u16*)(ws + 16*MB);
  u16*  v   = (u16*)(ws + 24*MB);
  u16*  a   = (u16*)(ws + 0*MB);    // reuse xn
  u16*  ao  = (u16*)(ws + 8*MB);    // reuse q
  u16*  z1  = (u16*)(ws + 16*MB);   // reuse k
  float* h  = (float*)(ws + 32*MB);
  u16*  vt  = (u16*)(ws + 32*MB);   // Vt[64][64][1024]; dead before h is written
  u16*  t   = (u16*)(ws + 48*MB);   // [48,80), LN2048 in place
  u16* Wqb  = (u16*)(ws + 80*MB);
  u16* Wkb  = (u16*)(ws + 80*MB + 512*1024);
  u16* Wvb  = (u16*)(ws + 81*MB);
  u16* Wob  = (u16*)(ws + 81*MB + 512*1024);
  u16* W1b  = (u16*)(ws + 82*MB);
  u16* W2b  = (u16*)(ws + 84*MB);

  const int M = 8192;

  cvt_f32_bf16<<<128, 256, 0, stream>>>(Wq, Wqb, 512*512);
  cvt_f32_bf16<<<128, 256, 0, stream>>>(Wk, Wkb, 512*512);
  cvt_f32_bf16<<<128, 256, 0, stream>>>(Wv, Wvb, 512*512);
  cvt_f32_bf16<<<128, 256, 0, stream>>>(Wo, Wob, 512*512);
  cvt_f32_bf16<<<512, 256, 0, stream>>>(mW1, W1b, 2048*512);
  cvt_f32_bf16<<<512, 256, 0, stream>>>(mW2, W2b, 2048*512);

  ln512_kernel<<<2048, 256, 0, stream>>>(x, n1w, n1b, xn);

  gemm_bt<EPI_NONE,u16><<<dim3(4,64), 256, 0, stream>>>(xn, Wqb, nullptr, nullptr, q, M, 512, 512);
  gemm_bt<EPI_NONE,u16><<<dim3(4,64), 256, 0, stream>>>(xn, Wkb, nullptr, nullptr, k, M, 512, 512);
  gemm_bt<EPI_NONE,u16><<<dim3(4,64), 256, 0, stream>>>(xn, Wvb, nullptr, nullptr, v, M, 512, 512);

  transpose_v<<<1024, 256, 0, stream>>>(v, vt);

  attn_mfma<<<1024, 256, 0, stream>>>(q, k, vt, lq1, lk1, lq2, lk2, subw, a);

  gemm_bt<EPI_NONE,u16><<<dim3(4,64), 256, 0, stream>>>(a, Wob, nullptr, nullptr, ao, M, 512, 512);

  lnres_kernel<<<2048, 256, 0, stream>>>(ao, x, n2w, n2b, m1w, m1b, h, z1);

  gemm_bt<EPI_BIAS_GELU,u16><<<dim3(16,64), 256, 0, stream>>>(z1, W1b, mb1, nullptr, t, M, 2048, 512);

  ln2048_kernel<<<2048, 256, 0, stream>>>(t, m2w, m2b, t);

  gemm_bt<EPI_BIAS_RES,float><<<dim3(4,64), 256, 0, stream>>>(t, W2b, mb2, h, out, M, 512, 2048);
}

// Round 5
// 336.087 us; speedup vs baseline: 1.2777x; 1.1043x over previous
//
#include <hip/hip_runtime.h>
#include <cstdint>
#include <cstddef>

typedef unsigned short u16;
typedef unsigned int   u32;
typedef __attribute__((ext_vector_type(8))) short short8;
typedef __attribute__((ext_vector_type(4))) float floatx4;

__device__ __forceinline__ float asf(u32 u){ union{u32 u; float f;} v; v.u=u; return v.f; }
__device__ __forceinline__ u32 asu(float f){ union{float f; u32 u;} v; v.f=f; return v.u; }
__device__ __forceinline__ u16 f2bf(float f){ u32 u = asu(f); u32 r = u + 0x7FFFu + ((u>>16)&1u); return (u16)(r>>16); }
__device__ __forceinline__ u32 pack2(float a, float b){ return (u32)f2bf(a) | (((u32)f2bf(b))<<16); }
__device__ __forceinline__ void bf8f(uint4 d, float* o){
  o[0]=asf(d.x<<16); o[1]=asf(d.x&0xFFFF0000u);
  o[2]=asf(d.y<<16); o[3]=asf(d.y&0xFFFF0000u);
  o[4]=asf(d.z<<16); o[5]=asf(d.z&0xFFFF0000u);
  o[6]=asf(d.w<<16); o[7]=asf(d.w&0xFFFF0000u);
}

// ---------------------------------------------------------------------------
// fp32 -> bf16 weight conversion, ALL weights in one launch.
// Segments: [0,128) Wq->Wqkv[0:512), [128,256) Wk->Wqkv[512:1024),
// [256,384) Wv->Wqkv[1024:1536), [384,512) Wo, [512,1024) W1, [1024,1536) W2.
// ---------------------------------------------------------------------------
__global__ __launch_bounds__(256) void cvt_all(
    const float* __restrict__ Wq, const float* __restrict__ Wk,
    const float* __restrict__ Wv, const float* __restrict__ Wo,
    const float* __restrict__ W1, const float* __restrict__ W2,
    u16* __restrict__ Wqkv, u16* __restrict__ Wob,
    u16* __restrict__ W1b, u16* __restrict__ W2b)
{
  const int blk = blockIdx.x;
  const float* src; u16* dst; int off;
  if      (blk < 128)  { src = Wq; dst = Wqkv;          off = blk; }
  else if (blk < 256)  { src = Wk; dst = Wqkv + 262144; off = blk - 128; }
  else if (blk < 384)  { src = Wv; dst = Wqkv + 524288; off = blk - 256; }
  else if (blk < 512)  { src = Wo; dst = Wob;           off = blk - 384; }
  else if (blk < 1024) { src = W1; dst = W1b;           off = blk - 512; }
  else                 { src = W2; dst = W2b;           off = blk - 1024; }
  const int i = (off*256 + threadIdx.x)*8;
  const float4 a = *(const float4*)(src + i);
  const float4 b = *(const float4*)(src + i + 4);
  uint4 st;
  st.x = pack2(a.x, a.y); st.y = pack2(a.z, a.w);
  st.z = pack2(b.x, b.y); st.w = pack2(b.z, b.w);
  *(uint4*)(dst + i) = st;
}

// ---------------------------------------------------------------------------
// MFMA GEMM: C[M,N] = A[M,K] @ B[N,K]^T, bf16 in, fp32 accum.
// 128x128 tile, BK=32, 4 waves, each wave 64x64 (4x4 of 16x16x32 MFMA).
// ---------------------------------------------------------------------------
enum { EPI_NONE=0, EPI_BIAS_GELU=1, EPI_BIAS_RES=2 };

template<int EPI, typename OutT>
__global__ __launch_bounds__(256) void gemm_bt(
    const u16* __restrict__ A, const u16* __restrict__ B,
    const float* __restrict__ bias, const float* __restrict__ res,
    OutT* __restrict__ C, int M, int N, int K)
{
  __shared__ u16 As[128*32];
  __shared__ u16 Bs[128*32];
  const int tid  = threadIdx.x;
  const int wave = tid >> 6;
  const int lane = tid & 63;
  const int bm = blockIdx.y, bn = blockIdx.x;

  const int srow = wave*16 + (lane>>2);
  const int scol = (lane&3)*8;
  const u16* Ag = A + (size_t)bm*128*K;
  const u16* Bg = B + (size_t)bn*128*K;

  const int wm = (wave>>1)*64;
  const int wn = (wave&1)*64;
  const int fr = lane & 15;
  const int fk = (lane>>4)*8;

  floatx4 acc[4][4] = {};

  for (int k0 = 0; k0 < K; k0 += 32) {
    __syncthreads();
    #pragma unroll
    for (int t = 0; t < 2; ++t) {
      __builtin_amdgcn_global_load_lds(
          (__attribute__((address_space(1))) void*)(Ag + (t*64 + srow)*K + k0 + scol),
          (__attribute__((address_space(3))) void*)(As + (t*64 + wave*16)*32),
          16, 0, 0);
      __builtin_amdgcn_global_load_lds(
          (__attribute__((address_space(1))) void*)(Bg + (t*64 + srow)*K + k0 + scol),
          (__attribute__((address_space(3))) void*)(Bs + (t*64 + wave*16)*32),
          16, 0, 0);
    }
    __syncthreads();

    short8 af[4], bfr[4];
    #pragma unroll
    for (int i=0;i<4;i++) af[i]  = *(const short8*)(As + (wm + i*16 + fr)*32 + fk);
    #pragma unroll
    for (int j=0;j<4;j++) bfr[j] = *(const short8*)(Bs + (wn + j*16 + fr)*32 + fk);
    #pragma unroll
    for (int i=0;i<4;i++)
      #pragma unroll
      for (int j=0;j<4;j++)
        acc[i][j] = __builtin_amdgcn_mfma_f32_16x16x32_bf16(af[i], bfr[j], acc[i][j], 0, 0, 0);
  }

  const int col0 = bn*128 + wn + fr;
  float bv[4] = {0.f,0.f,0.f,0.f};
  if constexpr (EPI != EPI_NONE) {
    #pragma unroll
    for (int j=0;j<4;j++) bv[j] = bias[col0 + j*16];
  }
  const int rq = (lane>>4)*4;
  #pragma unroll
  for (int i=0;i<4;i++){
    #pragma unroll
    for (int rr=0;rr<4;rr++){
      const int m = bm*128 + wm + i*16 + rq + rr;
      const size_t rowoff = (size_t)m*N;
      #pragma unroll
      for (int j=0;j<4;j++){
        float vv = acc[i][j][rr];
        const int n = col0 + j*16;
        if constexpr (EPI == EPI_BIAS_GELU){
          vv += bv[j];
          vv = 0.5f*vv*(1.f + erff(vv*0.70710678118654752f));
        } else if constexpr (EPI == EPI_BIAS_RES){
          vv += bv[j] + res[rowoff + n];
        }
        if constexpr (sizeof(OutT) == 2) C[rowoff + n] = f2bf(vv);
        else                             C[rowoff + n] = vv;
      }
    }
  }
}

// ---------------------------------------------------------------------------
// LayerNorm over 512 (fp32 in, bf16 out), wave-per-row, 4 rows/block
// ---------------------------------------------------------------------------
__global__ __launch_bounds__(256) void ln512_kernel(
    const float* __restrict__ x, const float* __restrict__ w, const float* __restrict__ b,
    u16* __restrict__ out)
{
  const int row  = blockIdx.x*4 + (threadIdx.x>>6);
  const int lane = threadIdx.x & 63;
  const size_t base = (size_t)row*512 + lane*8;
  float v[8];
  { const float4 a = *(const float4*)(x + base);
    const float4 c = *(const float4*)(x + base + 4);
    v[0]=a.x; v[1]=a.y; v[2]=a.z; v[3]=a.w; v[4]=c.x; v[5]=c.y; v[6]=c.z; v[7]=c.w; }
  float s=0.f, sq=0.f;
  #pragma unroll
  for (int i=0;i<8;i++){ s += v[i]; sq += v[i]*v[i]; }
  for (int off=32; off>0; off>>=1){ s += __shfl_xor(s, off, 64); sq += __shfl_xor(sq, off, 64); }
  const float mu = s*(1.f/512.f);
  const float rs = rsqrtf(sq*(1.f/512.f) - mu*mu + 1e-5f);
  float o[8];
  #pragma unroll
  for (int i=0;i<8;i++)
    o[i] = (v[i]-mu)*rs*w[lane*8+i] + b[lane*8+i];
  uint4 st; st.x=pack2(o[0],o[1]); st.y=pack2(o[2],o[3]); st.z=pack2(o[4],o[5]); st.w=pack2(o[6],o[7]);
  *(uint4*)(out + base) = st;
}

// h = LN(ao)*w2+b2 + x (fp32 out) ; z = LN(h)*w3+b3 (bf16 out)
__global__ __launch_bounds__(256) void lnres_kernel(
    const u16* __restrict__ ao, const float* __restrict__ x,
    const float* __restrict__ w2, const float* __restrict__ b2,
    const float* __restrict__ w3, const float* __restrict__ b3,
    float* __restrict__ h, u16* __restrict__ z)
{
  const int row  = blockIdx.x*4 + (threadIdx.x>>6);
  const int lane = threadIdx.x & 63;
  const size_t base = (size_t)row*512 + lane*8;
  float a[8], xr[8];
  bf8f(*(const uint4*)(ao + base), a);
  { const float4 p = *(const float4*)(x + base);
    const float4 q = *(const float4*)(x + base + 4);
    xr[0]=p.x; xr[1]=p.y; xr[2]=p.z; xr[3]=p.w; xr[4]=q.x; xr[5]=q.y; xr[6]=q.z; xr[7]=q.w; }
  float s=0.f, sq=0.f;
  #pragma unroll
  for (int i=0;i<8;i++){ s += a[i]; sq += a[i]*a[i]; }
  for (int off=32; off>0; off>>=1){ s += __shfl_xor(s, off, 64); sq += __shfl_xor(sq, off, 64); }
  float mu = s*(1.f/512.f);
  float rs = rsqrtf(sq*(1.f/512.f) - mu*mu + 1e-5f);
  float hv[8];
  #pragma unroll
  for (int i=0;i<8;i++)
    hv[i] = (a[i]-mu)*rs*w2[lane*8+i] + b2[lane*8+i] + xr[i];
  { float4 p; p.x=hv[0]; p.y=hv[1]; p.z=hv[2]; p.w=hv[3];
    float4 q; q.x=hv[4]; q.y=hv[5]; q.z=hv[6]; q.w=hv[7];
    *(float4*)(h + base) = p; *(float4*)(h + base + 4) = q; }
  s=0.f; sq=0.f;
  #pragma unroll
  for (int i=0;i<8;i++){ s += hv[i]; sq += hv[i]*hv[i]; }
  for (int off=32; off>0; off>>=1){ s += __shfl_xor(s, off, 64); sq += __shfl_xor(sq, off, 64); }
  mu = s*(1.f/512.f);
  rs = rsqrtf(sq*(1.f/512.f) - mu*mu + 1e-5f);
  float zv[8];
  #pragma unroll
  for (int i=0;i<8;i++)
    zv[i] = (hv[i]-mu)*rs*w3[lane*8+i] + b3[lane*8+i];
  uint4 st; st.x=pack2(zv[0],zv[1]); st.y=pack2(zv[2],zv[3]); st.z=pack2(zv[4],zv[5]); st.w=pack2(zv[6],zv[7]);
  *(uint4*)(z + base) = st;
}

// LayerNorm over 2048 (bf16, in place safe)
__global__ __launch_bounds__(256) void ln2048_kernel(
    const u16* x, const float* __restrict__ w, const float* __restrict__ b,
    u16* out)
{
  const int row  = blockIdx.x*4 + (threadIdx.x>>6);
  const int lane = threadIdx.x & 63;
  const u16* xp = x + (size_t)row*2048;
  float v[32];
  #pragma unroll
  for (int g=0; g<4; ++g) bf8f(*(const uint4*)(xp + g*512 + lane*8), v + g*8);
  float s=0.f, sq=0.f;
  #pragma unroll
  for (int i=0;i<32;i++){ s += v[i]; sq += v[i]*v[i]; }
  for (int off=32; off>0; off>>=1){ s += __shfl_xor(s, off, 64); sq += __shfl_xor(sq, off, 64); }
  const float mu = s*(1.f/2048.f);
  const float rs = rsqrtf(sq*(1.f/2048.f) - mu*mu + 1e-5f);
  u16* op = out + (size_t)row*2048;
  #pragma unroll
  for (int g=0; g<4; ++g){
    float o[8];
    #pragma unroll
    for (int i=0;i<8;i++){
      const int idx = g*512 + lane*8 + i;
      o[i] = (v[g*8+i]-mu)*rs*w[idx] + b[idx];
    }
    uint4 st; st.x=pack2(o[0],o[1]); st.y=pack2(o[2],o[3]); st.z=pack2(o[4],o[5]); st.w=pack2(o[6],o[7]);
    *(uint4*)(op + g*512 + lane*8) = st;
  }
}

// ---------------------------------------------------------------------------
// V transpose: QKV[8192 tok][1536] (v at col 1024) -> Vt[bh 64][dim 64][key 1024].
// ---------------------------------------------------------------------------
__global__ __launch_bounds__(256) void transpose_v(
    const u16* __restrict__ QKV, u16* __restrict__ Vt)
{
  __shared__ __align__(16) u16 T[64][72];   // pad 72 -> column reads spread banks
  const int bid = blockIdx.x;
  const int bh  = bid >> 4;     // 0..63
  const int kt  = bid & 15;     // 64-key tile
  const int b   = bh >> 3;
  const int h   = bh & 7;
  const int tid = threadIdx.x;

  const int key = tid >> 2;
  const int dc  = (tid & 3) * 16;
  const u16* src = QKV + ((size_t)(b*1024 + kt*64 + key))*1536 + 1024 + h*64 + dc;
  const uint4 a0 = *(const uint4*)(src);
  const uint4 a1 = *(const uint4*)(src + 8);
  *(uint4*)(&T[key][dc])     = a0;
  *(uint4*)(&T[key][dc + 8]) = a1;
  __syncthreads();

  const int d  = tid >> 2;
  const int kc = (tid & 3) * 16;
  union { uint4 q[2]; u16 us[16]; } ow;
  #pragma unroll
  for (int i=0;i<16;i++) ow.us[i] = T[kc + i][d];
  u16* dst = Vt + ((size_t)(bh*64 + d))*1024 + kt*64 + kc;
  *(uint4*)(dst)     = ow.q[0];
  *(uint4*)(dst + 8) = ow.q[1];
}

// ---------------------------------------------------------------------------
// MFMA differential flash attention — R13.
// Numeric path IDENTICAL to R11 (verified: __expf + scalar f2bf P-stores).
// Only change vs R11: Q/K read from fused QKV buffer (row stride 1536,
// K at col 512). K+Vt double-buffered LDS via global_load_lds, 1 barrier
// per tile, XOR-swizzled reads, deferred denominators.
// ---------------------------------------------------------------------------
#define ATT_SCALE 0.17677669529663687f   // 32^-0.5

__global__ __launch_bounds__(256) void attn_mfma(
    const u16* __restrict__ QKV, const u16* __restrict__ Vt,
    const float* __restrict__ lq1, const float* __restrict__ lk1,
    const float* __restrict__ lq2, const float* __restrict__ lk2,
    const float* __restrict__ subw, u16* __restrict__ out)
{
  __shared__ __align__(16) u16 Ks1[2][64*32];   // [buf][key][dim 0..31]  8 KB
  __shared__ __align__(16) u16 Ks2[2][64*32];   // [buf][key][dim 32..63] 8 KB
  __shared__ __align__(16) u16 Vs [2][64*64];   // [buf][dim][key 0..63] 16 KB
  __shared__ __align__(16) u16 Ps [2][4][16*32];// [sub][wave][row*32]    8 KB

  const int tid  = threadIdx.x;
  const int wave = tid >> 6;
  const int lane = tid & 63;
  const int quad = lane >> 4;
  const int l15  = lane & 15;

  const int bid = blockIdx.x;
  const int bh  = bid >> 4;
  const int qt  = bid & 15;
  const int b   = bh >> 3;
  const int h   = bh & 7;

  float t1 = 0.f, t2 = 0.f;
  for (int i=0;i<32;i++){ t1 += lq1[i]*lk1[i]; t2 += lq2[i]*lk2[i]; }
  const float lam = __expf(t1) - __expf(t2) + 0.2f;   // LAMBDA_INIT = 0.2

  // Q A-fragments from QKV (col 0..511): m = l15 (q row), k = quad*8..+8
  const int qrowg = b*1024 + qt*64 + wave*16 + l15;
  const short8 aq1 = *(const short8*)(QKV + (size_t)qrowg*1536 + 2*h*32 + quad*8);
  const short8 aq2 = *(const short8*)(QKV + (size_t)qrowg*1536 + 2*h*32 + 32 + quad*8);

  floatx4 O1[4] = {}, O2[4] = {};
  float l1acc[4] = {0.f,0.f,0.f,0.f};
  float l2acc[4] = {0.f,0.f,0.f,0.f};
  const floatx4 zf4 = {0.f,0.f,0.f,0.f};

  const int kvbase = b*1024;
  u16* pw1 = &Ps[0][wave][0];
  u16* pw2 = &Ps[1][wave][0];

  // --- staging geometry ---
  // K (col 512..1023): lane -> LDS row wave*16+(lane>>2), slot lane&3; src XOR'd.
  const int kchunk = ((lane&3) ^ ((lane>>3)&3)) * 8;
  const u16* KbaseS = QKV + (size_t)(kvbase + wave*16 + (lane>>2))*1536 + 512 + 2*h*32 + kchunk;
  // V: op o stages LDS rows wave*16+o*8+(lane>>3), slot lane&7; src XOR'd.
  const int vchunk = ((lane&7) ^ (lane>>3)) * 8;
  const u16* VbaseS = Vt + ((size_t)bh*64 + wave*16 + (lane>>3))*1024 + vchunk;

  #define STAGE_TILE(buf, tt)                                                     \
    do {                                                                          \
      const u16* kp = KbaseS + (size_t)(tt)*64*1536;                              \
      __builtin_amdgcn_global_load_lds(                                           \
          (__attribute__((address_space(1))) void*)(kp),                          \
          (__attribute__((address_space(3))) void*)(&Ks1[buf][wave*16*32]), 16, 0, 0); \
      __builtin_amdgcn_global_load_lds(                                           \
          (__attribute__((address_space(1))) void*)(kp + 32),                     \
          (__attribute__((address_space(3))) void*)(&Ks2[buf][wave*16*32]), 16, 0, 0); \
      const u16* vp = VbaseS + (tt)*64;                                           \
      __builtin_amdgcn_global_load_lds(                                           \
          (__attribute__((address_space(1))) void*)(vp),                          \
          (__attribute__((address_space(3))) void*)(&Vs[buf][wave*16*64]), 16, 0, 0); \
      __builtin_amdgcn_global_load_lds(                                           \
          (__attribute__((address_space(1))) void*)(vp + (size_t)8*1024),         \
          (__attribute__((address_space(3))) void*)(&Vs[buf][(wave*16+8)*64]), 16, 0, 0); \
    } while (0)

  // prologue: stage tile 0 into buf 0
  STAGE_TILE(0, 0);
  __syncthreads();   // vmcnt drain -> tile 0 visible

  // read-side swizzled offsets
  const int kslotR = (quad ^ ((l15>>1)&3)) * 8;          // K B-frag slot
  const int pslotR = ((quad + (l15>>2)) & 3) * 8;        // P A-frag slot (rotate)

  for (int t = 0; t < 16; ++t) {
    const int cur = t & 1;

    // ---- stage tile t+1 into the other buffer (async; drained at barrier)
    if (t < 15) STAGE_TILE(cur^1, t+1);

    // ---- two khalves, sequential (Ps shared; wave-local in-order DS ops)
    #pragma unroll
    for (int kh = 0; kh < 2; ++kh) {
      // QK^T -> exp -> Ps (rotated slots); denominators per-lane
      #pragma unroll
      for (int ktl = 0; ktl < 2; ++ktl) {
        const int kt = kh*2 + ktl;
        const short8 bk1 = *(const short8*)(&Ks1[cur][(kt*16 + l15)*32 + kslotR]);
        const short8 bk2 = *(const short8*)(&Ks2[cur][(kt*16 + l15)*32 + kslotR]);
        const floatx4 s1 = __builtin_amdgcn_mfma_f32_16x16x32_bf16(aq1, bk1, zf4, 0, 0, 0);
        const floatx4 s2 = __builtin_amdgcn_mfma_f32_16x16x32_bf16(aq2, bk2, zf4, 0, 0, 0);
        const int wslot = ((ktl*2 + (l15>>3) + quad) & 3)*8;
        u16* d1 = pw1 + wslot + (l15&7);
        u16* d2 = pw2 + wslot + (l15&7);
        #pragma unroll
        for (int rr = 0; rr < 4; ++rr) {
          const float p1 = __expf(s1[rr]*ATT_SCALE);
          const float p2 = __expf(s2[rr]*ATT_SCALE);
          d1[(quad*4+rr)*32] = f2bf(p1);
          d2[(quad*4+rr)*32] = f2bf(p2);
          l1acc[rr] += p1;
          l2acc[rr] += p2;
        }
      }
      // P A-frags (wave-local RAW; compiler inserts lgkm waits)
      const short8 ap1 = *(const short8*)(pw1 + l15*32 + pslotR);
      const short8 ap2 = *(const short8*)(pw2 + l15*32 + pslotR);
      // PV: B = Vs, swizzled slot (kh*4+quad) ^ (l15&7)
      const int vslotR = ((kh*4 + quad) ^ (l15&7)) * 8;
      #pragma unroll
      for (int nt = 0; nt < 4; ++nt) {
        const short8 bv = *(const short8*)(&Vs[cur][(nt*16 + l15)*64 + vslotR]);
        O1[nt] = __builtin_amdgcn_mfma_f32_16x16x32_bf16(ap1, bv, O1[nt], 0, 0, 0);
        O2[nt] = __builtin_amdgcn_mfma_f32_16x16x32_bf16(ap2, bv, O2[nt], 0, 0, 0);
      }
    }

    // ---- single barrier: staging for t+1 complete + readers done with buf[cur]
    if (t < 15) __syncthreads();
  }
  #undef STAGE_TILE

  // deferred softmax-denominator reduce over the 16 key-lanes (once)
  #pragma unroll
  for (int rr=0; rr<4; ++rr){
    float v1 = l1acc[rr], v2 = l2acc[rr];
    v1 += __shfl_xor(v1, 1, 64); v2 += __shfl_xor(v2, 1, 64);
    v1 += __shfl_xor(v1, 2, 64); v2 += __shfl_xor(v2, 2, 64);
    v1 += __shfl_xor(v1, 4, 64); v2 += __shfl_xor(v2, 4, 64);
    v1 += __shfl_xor(v1, 8, 64); v2 += __shfl_xor(v2, 8, 64);
    l1acc[rr] = v1; l2acc[rr] = v2;
  }

  // --- epilogue: combine, rmsnorm over 64 dims, *0.8, store bf16
  float sw[4];
  #pragma unroll
  for (int nt=0; nt<4; ++nt) sw[nt] = subw[nt*16 + l15];

  #pragma unroll
  for (int rr=0; rr<4; ++rr){
    const int row = quad*4 + rr;
    const float il1 = 1.f / l1acc[rr];
    const float cl2 = lam / l2acc[rr];
    float o[4]; float ss = 0.f;
    #pragma unroll
    for (int nt=0; nt<4; ++nt){
      o[nt] = O1[nt][rr]*il1 - O2[nt][rr]*cl2;
      ss += o[nt]*o[nt];
    }
    ss += __shfl_xor(ss, 1, 64);
    ss += __shfl_xor(ss, 2, 64);
    ss += __shfl_xor(ss, 4, 64);
    ss += __shfl_xor(ss, 8, 64);
    const float rs = rsqrtf(ss*(1.f/64.f) + 1e-5f) * 0.8f;
    const int orow = b*1024 + qt*64 + wave*16 + row;
    u16* op = out + (size_t)orow*512 + h*64 + l15;
    #pragma unroll
    for (int nt=0; nt<4; ++nt)
      op[nt*16] = f2bf(o[nt]*rs*sw[nt]);
  }
}

// ---------------------------------------------------------------------------
extern "C" void kernel_launch(void* const* d_in, const int* in_sizes, int n_in,
                              void* d_out, int out_size, void* d_ws, size_t ws_size,
                              hipStream_t stream)
{
  (void)in_sizes; (void)n_in; (void)out_size; (void)ws_size;
  const float* x    = (const float*)d_in[0];
  const float* Wq   = (const float*)d_in[1];
  const float* Wk   = (const float*)d_in[2];
  const float* Wv   = (const float*)d_in[3];
  const float* Wo   = (const float*)d_in[4];
  const float* lq1  = (const float*)d_in[5];
  const float* lk1  = (const float*)d_in[6];
  const float* lq2  = (const float*)d_in[7];
  const float* lk2  = (const float*)d_in[8];
  const float* subw = (const float*)d_in[9];
  const float* n1w  = (const float*)d_in[10];
  const float* n1b  = (const float*)d_in[11];
  const float* n2w  = (const float*)d_in[12];
  const float* n2b  = (const float*)d_in[13];
  const float* m1w  = (const float*)d_in[14];
  const float* m1b  = (const float*)d_in[15];
  const float* mW1  = (const float*)d_in[16];
  const float* mb1  = (const float*)d_in[17];
  const float* m2w  = (const float*)d_in[18];
  const float* m2b  = (const float*)d_in[19];
  const float* mW2  = (const float*)d_in[20];
  const float* mb2  = (const float*)d_in[21];
  float* out = (float*)d_out;   // fp32 output

  char* ws = (char*)d_ws;
  const size_t MB = (size_t)1 << 20;
  u16*  xn  = (u16*)(ws + 0*MB);
  u16*  qkv = (u16*)(ws + 8*MB);    // [8192][1536] bf16 = 24 MB -> [8,32)
  u16*  a   = (u16*)(ws + 0*MB);    // attn out, reuse xn
  u16*  ao  = (u16*)(ws + 8*MB);    // reuse qkv (dead after attn)
  u16*  z1  = (u16*)(ws + 16*MB);
  float* h  = (float*)(ws + 32*MB);
  u16*  vt  = (u16*)(ws + 32*MB);   // Vt[64][64][1024]; dead before h written
  u16*  t   = (u16*)(ws + 48*MB);   // [48,80), LN2048 in place
  u16* Wqkvb= (u16*)(ws + 80*MB);   // [1536][512] bf16 = 1.5 MB
  u16* Wob  = (u16*)(ws + 81*MB + 512*1024);
  u16* W1b  = (u16*)(ws + 82*MB);
  u16* W2b  = (u16*)(ws + 84*MB);

  const int M = 8192;

  cvt_all<<<1536, 256, 0, stream>>>(Wq, Wk, Wv, Wo, mW1, mW2, Wqkvb, Wob, W1b, W2b);

  ln512_kernel<<<2048, 256, 0, stream>>>(x, n1w, n1b, xn);

  // fused QKV GEMM: [8192][1536] = xn @ concat(Wq,Wk,Wv)^T ; 768 blocks = 3/CU
  gemm_bt<EPI_NONE,u16><<<dim3(12,64), 256, 0, stream>>>(xn, Wqkvb, nullptr, nullptr, qkv, M, 1536, 512);

  transpose_v<<<1024, 256, 0, stream>>>(qkv, vt);

  attn_mfma<<<1024, 256, 0, stream>>>(qkv, vt, lq1, lk1, lq2, lk2, subw, a);

  gemm_bt<EPI_NONE,u16><<<dim3(4,64), 256, 0, stream>>>(a, Wob, nullptr, nullptr, ao, M, 512, 512);

  lnres_kernel<<<2048, 256, 0, stream>>>(ao, x, n2w, n2b, m1w, m1b, h, z1);

  gemm_bt<EPI_BIAS_GELU,u16><<<dim3(16,64), 256, 0, stream>>>(z1, W1b, mb1, nullptr, t, M, 2048, 512);

  ln2048_kernel<<<2048, 256, 0, stream>>>(t, m2w, m2b, t);

  gemm_bt<EPI_BIAS_RES,float><<<dim3(4,64), 256, 0, stream>>>(t, W2b, mb2, h, out, M, 512, 2048);
}

// Round 6
// 322.978 us; speedup vs baseline: 1.3296x; 1.0406x over previous
//
#include <hip/hip_runtime.h>
#include <cstdint>
#include <cstddef>

typedef unsigned short u16;
typedef unsigned int   u32;
typedef __attribute__((ext_vector_type(8))) short short8;
typedef __attribute__((ext_vector_type(4))) float floatx4;

__device__ __forceinline__ float asf(u32 u){ union{u32 u; float f;} v; v.u=u; return v.f; }
__device__ __forceinline__ u32 asu(float f){ union{float f; u32 u;} v; v.f=f; return v.u; }
__device__ __forceinline__ u16 f2bf(float f){ u32 u = asu(f); u32 r = u + 0x7FFFu + ((u>>16)&1u); return (u16)(r>>16); }
// fast bf16: round-to-nearest, ties away (2 VALU ops; differs from RNE only on exact ties)
__device__ __forceinline__ u16 f2bf_fast(float f){ return (u16)((asu(f) + 0x8000u)>>16); }
__device__ __forceinline__ u32 pack2(float a, float b){ return (u32)f2bf(a) | (((u32)f2bf(b))<<16); }
__device__ __forceinline__ void bf8f(uint4 d, float* o){
  o[0]=asf(d.x<<16); o[1]=asf(d.x&0xFFFF0000u);
  o[2]=asf(d.y<<16); o[3]=asf(d.y&0xFFFF0000u);
  o[4]=asf(d.z<<16); o[5]=asf(d.z&0xFFFF0000u);
  o[6]=asf(d.w<<16); o[7]=asf(d.w&0xFFFF0000u);
}

// ---------------------------------------------------------------------------
// fp32 -> bf16 weight conversion, ALL weights in one launch.
// ---------------------------------------------------------------------------
__global__ __launch_bounds__(256) void cvt_all(
    const float* __restrict__ Wq, const float* __restrict__ Wk,
    const float* __restrict__ Wv, const float* __restrict__ Wo,
    const float* __restrict__ W1, const float* __restrict__ W2,
    u16* __restrict__ Wqkv, u16* __restrict__ Wob,
    u16* __restrict__ W1b, u16* __restrict__ W2b)
{
  const int blk = blockIdx.x;
  const float* src; u16* dst; int off;
  if      (blk < 128)  { src = Wq; dst = Wqkv;          off = blk; }
  else if (blk < 256)  { src = Wk; dst = Wqkv + 262144; off = blk - 128; }
  else if (blk < 384)  { src = Wv; dst = Wqkv + 524288; off = blk - 256; }
  else if (blk < 512)  { src = Wo; dst = Wob;           off = blk - 384; }
  else if (blk < 1024) { src = W1; dst = W1b;           off = blk - 512; }
  else                 { src = W2; dst = W2b;           off = blk - 1024; }
  const int i = (off*256 + threadIdx.x)*8;
  const float4 a = *(const float4*)(src + i);
  const float4 b = *(const float4*)(src + i + 4);
  uint4 st;
  st.x = pack2(a.x, a.y); st.y = pack2(a.z, a.w);
  st.z = pack2(b.x, b.y); st.w = pack2(b.z, b.w);
  *(uint4*)(dst + i) = st;
}

// ---------------------------------------------------------------------------
// MFMA GEMM: C[M,N] = A[M,K] @ B[N,K]^T, bf16 in, fp32 accum.
// 128x128 tile, BK=32, 4 waves, each wave 64x64 (4x4 of 16x16x32 MFMA).
// R14: K-step DOUBLE-BUFFERED (R11-verified attn pattern): stage t+1 at top
// of step t via global_load_lds, ONE barrier per step. Staging latency hides
// under ds_read+MFMA — essential at 1 block/CU (N=512 GEMMs) where no
// inter-block overlap exists. LDS 32 KB.
// ---------------------------------------------------------------------------
enum { EPI_NONE=0, EPI_BIAS_GELU=1, EPI_BIAS_RES=2 };

template<int EPI, typename OutT>
__global__ __launch_bounds__(256) void gemm_bt(
    const u16* __restrict__ A, const u16* __restrict__ B,
    const float* __restrict__ bias, const float* __restrict__ res,
    OutT* __restrict__ C, int M, int N, int K)
{
  __shared__ u16 As[2][128*32];
  __shared__ u16 Bs[2][128*32];
  const int tid  = threadIdx.x;
  const int wave = tid >> 6;
  const int lane = tid & 63;
  const int bm = blockIdx.y, bn = blockIdx.x;

  const int srow = wave*16 + (lane>>2);
  const int scol = (lane&3)*8;
  const u16* Ag = A + (size_t)bm*128*K;
  const u16* Bg = B + (size_t)bn*128*K;

  const int wm = (wave>>1)*64;
  const int wn = (wave&1)*64;
  const int fr = lane & 15;
  const int fk = (lane>>4)*8;

  floatx4 acc[4][4] = {};

  #define G_STAGE(buf, kk)                                                        \
    do {                                                                          \
      _Pragma("unroll")                                                           \
      for (int tt = 0; tt < 2; ++tt) {                                            \
        __builtin_amdgcn_global_load_lds(                                         \
            (__attribute__((address_space(1))) void*)(Ag + (tt*64 + srow)*K + (kk) + scol), \
            (__attribute__((address_space(3))) void*)(&As[buf][(tt*64 + wave*16)*32]),      \
            16, 0, 0);                                                            \
        __builtin_amdgcn_global_load_lds(                                         \
            (__attribute__((address_space(1))) void*)(Bg + (tt*64 + srow)*K + (kk) + scol), \
            (__attribute__((address_space(3))) void*)(&Bs[buf][(tt*64 + wave*16)*32]),      \
            16, 0, 0);                                                            \
      }                                                                           \
    } while (0)

  // prologue: stage k0=0 into buf 0; barrier drains vmcnt
  G_STAGE(0, 0);
  __syncthreads();

  const int nsteps = K >> 5;
  for (int s = 0; s < nsteps; ++s) {
    const int cur = s & 1;
    if (s + 1 < nsteps) G_STAGE(cur^1, (s+1)*32);

    short8 af[4], bfr[4];
    #pragma unroll
    for (int i=0;i<4;i++) af[i]  = *(const short8*)(&As[cur][(wm + i*16 + fr)*32 + fk]);
    #pragma unroll
    for (int j=0;j<4;j++) bfr[j] = *(const short8*)(&Bs[cur][(wn + j*16 + fr)*32 + fk]);
    #pragma unroll
    for (int i=0;i<4;i++)
      #pragma unroll
      for (int j=0;j<4;j++)
        acc[i][j] = __builtin_amdgcn_mfma_f32_16x16x32_bf16(af[i], bfr[j], acc[i][j], 0, 0, 0);

    // one barrier: staging for s+1 complete (vmcnt drain) + all waves done
    // reading buf[cur] before it is overwritten at step s+1
    if (s + 1 < nsteps) __syncthreads();
  }
  #undef G_STAGE

  const int col0 = bn*128 + wn + fr;
  float bv[4] = {0.f,0.f,0.f,0.f};
  if constexpr (EPI != EPI_NONE) {
    #pragma unroll
    for (int j=0;j<4;j++) bv[j] = bias[col0 + j*16];
  }
  const int rq = (lane>>4)*4;
  #pragma unroll
  for (int i=0;i<4;i++){
    #pragma unroll
    for (int rr=0;rr<4;rr++){
      const int m = bm*128 + wm + i*16 + rq + rr;
      const size_t rowoff = (size_t)m*N;
      #pragma unroll
      for (int j=0;j<4;j++){
        float vv = acc[i][j][rr];
        const int n = col0 + j*16;
        if constexpr (EPI == EPI_BIAS_GELU){
          vv += bv[j];
          vv = 0.5f*vv*(1.f + erff(vv*0.70710678118654752f));
        } else if constexpr (EPI == EPI_BIAS_RES){
          vv += bv[j] + res[rowoff + n];
        }
        if constexpr (sizeof(OutT) == 2) C[rowoff + n] = f2bf(vv);
        else                             C[rowoff + n] = vv;
      }
    }
  }
}

// ---------------------------------------------------------------------------
// LayerNorm over 512 (fp32 in, bf16 out), wave-per-row, 4 rows/block
// ---------------------------------------------------------------------------
__global__ __launch_bounds__(256) void ln512_kernel(
    const float* __restrict__ x, const float* __restrict__ w, const float* __restrict__ b,
    u16* __restrict__ out)
{
  const int row  = blockIdx.x*4 + (threadIdx.x>>6);
  const int lane = threadIdx.x & 63;
  const size_t base = (size_t)row*512 + lane*8;
  float v[8];
  { const float4 a = *(const float4*)(x + base);
    const float4 c = *(const float4*)(x + base + 4);
    v[0]=a.x; v[1]=a.y; v[2]=a.z; v[3]=a.w; v[4]=c.x; v[5]=c.y; v[6]=c.z; v[7]=c.w; }
  float s=0.f, sq=0.f;
  #pragma unroll
  for (int i=0;i<8;i++){ s += v[i]; sq += v[i]*v[i]; }
  for (int off=32; off>0; off>>=1){ s += __shfl_xor(s, off, 64); sq += __shfl_xor(sq, off, 64); }
  const float mu = s*(1.f/512.f);
  const float rs = rsqrtf(sq*(1.f/512.f) - mu*mu + 1e-5f);
  float o[8];
  #pragma unroll
  for (int i=0;i<8;i++)
    o[i] = (v[i]-mu)*rs*w[lane*8+i] + b[lane*8+i];
  uint4 st; st.x=pack2(o[0],o[1]); st.y=pack2(o[2],o[3]); st.z=pack2(o[4],o[5]); st.w=pack2(o[6],o[7]);
  *(uint4*)(out + base) = st;
}

// h = LN(ao)*w2+b2 + x (fp32 out) ; z = LN(h)*w3+b3 (bf16 out)
__global__ __launch_bounds__(256) void lnres_kernel(
    const u16* __restrict__ ao, const float* __restrict__ x,
    const float* __restrict__ w2, const float* __restrict__ b2,
    const float* __restrict__ w3, const float* __restrict__ b3,
    float* __restrict__ h, u16* __restrict__ z)
{
  const int row  = blockIdx.x*4 + (threadIdx.x>>6);
  const int lane = threadIdx.x & 63;
  const size_t base = (size_t)row*512 + lane*8;
  float a[8], xr[8];
  bf8f(*(const uint4*)(ao + base), a);
  { const float4 p = *(const float4*)(x + base);
    const float4 q = *(const float4*)(x + base + 4);
    xr[0]=p.x; xr[1]=p.y; xr[2]=p.z; xr[3]=p.w; xr[4]=q.x; xr[5]=q.y; xr[6]=q.z; xr[7]=q.w; }
  float s=0.f, sq=0.f;
  #pragma unroll
  for (int i=0;i<8;i++){ s += a[i]; sq += a[i]*a[i]; }
  for (int off=32; off>0; off>>=1){ s += __shfl_xor(s, off, 64); sq += __shfl_xor(sq, off, 64); }
  float mu = s*(1.f/512.f);
  float rs = rsqrtf(sq*(1.f/512.f) - mu*mu + 1e-5f);
  float hv[8];
  #pragma unroll
  for (int i=0;i<8;i++)
    hv[i] = (a[i]-mu)*rs*w2[lane*8+i] + b2[lane*8+i] + xr[i];
  { float4 p; p.x=hv[0]; p.y=hv[1]; p.z=hv[2]; p.w=hv[3];
    float4 q; q.x=hv[4]; q.y=hv[5]; q.z=hv[6]; q.w=hv[7];
    *(float4*)(h + base) = p; *(float4*)(h + base + 4) = q; }
  s=0.f; sq=0.f;
  #pragma unroll
  for (int i=0;i<8;i++){ s += hv[i]; sq += hv[i]*hv[i]; }
  for (int off=32; off>0; off>>=1){ s += __shfl_xor(s, off, 64); sq += __shfl_xor(sq, off, 64); }
  mu = s*(1.f/512.f);
  rs = rsqrtf(sq*(1.f/512.f) - mu*mu + 1e-5f);
  float zv[8];
  #pragma unroll
  for (int i=0;i<8;i++)
    zv[i] = (hv[i]-mu)*rs*w3[lane*8+i] + b3[lane*8+i];
  uint4 st; st.x=pack2(zv[0],zv[1]); st.y=pack2(zv[2],zv[3]); st.z=pack2(zv[4],zv[5]); st.w=pack2(zv[6],zv[7]);
  *(uint4*)(z + base) = st;
}

// LayerNorm over 2048 (bf16, in place safe)
__global__ __launch_bounds__(256) void ln2048_kernel(
    const u16* x, const float* __restrict__ w, const float* __restrict__ b,
    u16* out)
{
  const int row  = blockIdx.x*4 + (threadIdx.x>>6);
  const int lane = threadIdx.x & 63;
  const u16* xp = x + (size_t)row*2048;
  float v[32];
  #pragma unroll
  for (int g=0; g<4; ++g) bf8f(*(const uint4*)(xp + g*512 + lane*8), v + g*8);
  float s=0.f, sq=0.f;
  #pragma unroll
  for (int i=0;i<32;i++){ s += v[i]; sq += v[i]*v[i]; }
  for (int off=32; off>0; off>>=1){ s += __shfl_xor(s, off, 64); sq += __shfl_xor(sq, off, 64); }
  const float mu = s*(1.f/2048.f);
  const float rs = rsqrtf(sq*(1.f/2048.f) - mu*mu + 1e-5f);
  u16* op = out + (size_t)row*2048;
  #pragma unroll
  for (int g=0; g<4; ++g){
    float o[8];
    #pragma unroll
    for (int i=0;i<8;i++){
      const int idx = g*512 + lane*8 + i;
      o[i] = (v[g*8+i]-mu)*rs*w[idx] + b[idx];
    }
    uint4 st; st.x=pack2(o[0],o[1]); st.y=pack2(o[2],o[3]); st.z=pack2(o[4],o[5]); st.w=pack2(o[6],o[7]);
    *(uint4*)(op + g*512 + lane*8) = st;
  }
}

// ---------------------------------------------------------------------------
// V transpose: QKV[8192 tok][1536] (v at col 1024) -> Vt[bh 64][dim 64][key 1024].
// ---------------------------------------------------------------------------
__global__ __launch_bounds__(256) void transpose_v(
    const u16* __restrict__ QKV, u16* __restrict__ Vt)
{
  __shared__ __align__(16) u16 T[64][72];
  const int bid = blockIdx.x;
  const int bh  = bid >> 4;
  const int kt  = bid & 15;
  const int b   = bh >> 3;
  const int h   = bh & 7;
  const int tid = threadIdx.x;

  const int key = tid >> 2;
  const int dc  = (tid & 3) * 16;
  const u16* src = QKV + ((size_t)(b*1024 + kt*64 + key))*1536 + 1024 + h*64 + dc;
  const uint4 a0 = *(const uint4*)(src);
  const uint4 a1 = *(const uint4*)(src + 8);
  *(uint4*)(&T[key][dc])     = a0;
  *(uint4*)(&T[key][dc + 8]) = a1;
  __syncthreads();

  const int d  = tid >> 2;
  const int kc = (tid & 3) * 16;
  union { uint4 q[2]; u16 us[16]; } ow;
  #pragma unroll
  for (int i=0;i<16;i++) ow.us[i] = T[kc + i][d];
  u16* dst = Vt + ((size_t)(bh*64 + d))*1024 + kt*64 + kc;
  *(uint4*)(dst)     = ow.q[0];
  *(uint4*)(dst + 8) = ow.q[1];
}

// ---------------------------------------------------------------------------
// MFMA differential flash attention — R14 (= R13 verified structure;
// only change: P-store conversion f2bf -> f2bf_fast, 2 VALU ops).
// ---------------------------------------------------------------------------
#define ATT_SCALE 0.17677669529663687f   // 32^-0.5

__global__ __launch_bounds__(256) void attn_mfma(
    const u16* __restrict__ QKV, const u16* __restrict__ Vt,
    const float* __restrict__ lq1, const float* __restrict__ lk1,
    const float* __restrict__ lq2, const float* __restrict__ lk2,
    const float* __restrict__ subw, u16* __restrict__ out)
{
  __shared__ __align__(16) u16 Ks1[2][64*32];   // [buf][key][dim 0..31]  8 KB
  __shared__ __align__(16) u16 Ks2[2][64*32];   // [buf][key][dim 32..63] 8 KB
  __shared__ __align__(16) u16 Vs [2][64*64];   // [buf][dim][key 0..63] 16 KB
  __shared__ __align__(16) u16 Ps [2][4][16*32];// [sub][wave][row*32]    8 KB

  const int tid  = threadIdx.x;
  const int wave = tid >> 6;
  const int lane = tid & 63;
  const int quad = lane >> 4;
  const int l15  = lane & 15;

  const int bid = blockIdx.x;
  const int bh  = bid >> 4;
  const int qt  = bid & 15;
  const int b   = bh >> 3;
  const int h   = bh & 7;

  float t1 = 0.f, t2 = 0.f;
  for (int i=0;i<32;i++){ t1 += lq1[i]*lk1[i]; t2 += lq2[i]*lk2[i]; }
  const float lam = __expf(t1) - __expf(t2) + 0.2f;   // LAMBDA_INIT = 0.2

  const int qrowg = b*1024 + qt*64 + wave*16 + l15;
  const short8 aq1 = *(const short8*)(QKV + (size_t)qrowg*1536 + 2*h*32 + quad*8);
  const short8 aq2 = *(const short8*)(QKV + (size_t)qrowg*1536 + 2*h*32 + 32 + quad*8);

  floatx4 O1[4] = {}, O2[4] = {};
  float l1acc[4] = {0.f,0.f,0.f,0.f};
  float l2acc[4] = {0.f,0.f,0.f,0.f};
  const floatx4 zf4 = {0.f,0.f,0.f,0.f};

  const int kvbase = b*1024;
  u16* pw1 = &Ps[0][wave][0];
  u16* pw2 = &Ps[1][wave][0];

  const int kchunk = ((lane&3) ^ ((lane>>3)&3)) * 8;
  const u16* KbaseS = QKV + (size_t)(kvbase + wave*16 + (lane>>2))*1536 + 512 + 2*h*32 + kchunk;
  const int vchunk = ((lane&7) ^ (lane>>3)) * 8;
  const u16* VbaseS = Vt + ((size_t)bh*64 + wave*16 + (lane>>3))*1024 + vchunk;

  #define STAGE_TILE(buf, tt)                                                     \
    do {                                                                          \
      const u16* kp = KbaseS + (size_t)(tt)*64*1536;                              \
      __builtin_amdgcn_global_load_lds(                                           \
          (__attribute__((address_space(1))) void*)(kp),                          \
          (__attribute__((address_space(3))) void*)(&Ks1[buf][wave*16*32]), 16, 0, 0); \
      __builtin_amdgcn_global_load_lds(                                           \
          (__attribute__((address_space(1))) void*)(kp + 32),                     \
          (__attribute__((address_space(3))) void*)(&Ks2[buf][wave*16*32]), 16, 0, 0); \
      const u16* vp = VbaseS + (tt)*64;                                           \
      __builtin_amdgcn_global_load_lds(                                           \
          (__attribute__((address_space(1))) void*)(vp),                          \
          (__attribute__((address_space(3))) void*)(&Vs[buf][wave*16*64]), 16, 0, 0); \
      __builtin_amdgcn_global_load_lds(                                           \
          (__attribute__((address_space(1))) void*)(vp + (size_t)8*1024),         \
          (__attribute__((address_space(3))) void*)(&Vs[buf][(wave*16+8)*64]), 16, 0, 0); \
    } while (0)

  STAGE_TILE(0, 0);
  __syncthreads();

  const int kslotR = (quad ^ ((l15>>1)&3)) * 8;
  const int pslotR = ((quad + (l15>>2)) & 3) * 8;

  for (int t = 0; t < 16; ++t) {
    const int cur = t & 1;

    if (t < 15) STAGE_TILE(cur^1, t+1);

    #pragma unroll
    for (int kh = 0; kh < 2; ++kh) {
      #pragma unroll
      for (int ktl = 0; ktl < 2; ++ktl) {
        const int kt = kh*2 + ktl;
        const short8 bk1 = *(const short8*)(&Ks1[cur][(kt*16 + l15)*32 + kslotR]);
        const short8 bk2 = *(const short8*)(&Ks2[cur][(kt*16 + l15)*32 + kslotR]);
        const floatx4 s1 = __builtin_amdgcn_mfma_f32_16x16x32_bf16(aq1, bk1, zf4, 0, 0, 0);
        const floatx4 s2 = __builtin_amdgcn_mfma_f32_16x16x32_bf16(aq2, bk2, zf4, 0, 0, 0);
        const int wslot = ((ktl*2 + (l15>>3) + quad) & 3)*8;
        u16* d1 = pw1 + wslot + (l15&7);
        u16* d2 = pw2 + wslot + (l15&7);
        #pragma unroll
        for (int rr = 0; rr < 4; ++rr) {
          const float p1 = __expf(s1[rr]*ATT_SCALE);
          const float p2 = __expf(s2[rr]*ATT_SCALE);
          d1[(quad*4+rr)*32] = f2bf_fast(p1);
          d2[(quad*4+rr)*32] = f2bf_fast(p2);
          l1acc[rr] += p1;
          l2acc[rr] += p2;
        }
      }
      const short8 ap1 = *(const short8*)(pw1 + l15*32 + pslotR);
      const short8 ap2 = *(const short8*)(pw2 + l15*32 + pslotR);
      const int vslotR = ((kh*4 + quad) ^ (l15&7)) * 8;
      #pragma unroll
      for (int nt = 0; nt < 4; ++nt) {
        const short8 bv = *(const short8*)(&Vs[cur][(nt*16 + l15)*64 + vslotR]);
        O1[nt] = __builtin_amdgcn_mfma_f32_16x16x32_bf16(ap1, bv, O1[nt], 0, 0, 0);
        O2[nt] = __builtin_amdgcn_mfma_f32_16x16x32_bf16(ap2, bv, O2[nt], 0, 0, 0);
      }
    }

    if (t < 15) __syncthreads();
  }
  #undef STAGE_TILE

  #pragma unroll
  for (int rr=0; rr<4; ++rr){
    float v1 = l1acc[rr], v2 = l2acc[rr];
    v1 += __shfl_xor(v1, 1, 64); v2 += __shfl_xor(v2, 1, 64);
    v1 += __shfl_xor(v1, 2, 64); v2 += __shfl_xor(v2, 2, 64);
    v1 += __shfl_xor(v1, 4, 64); v2 += __shfl_xor(v2, 4, 64);
    v1 += __shfl_xor(v1, 8, 64); v2 += __shfl_xor(v2, 8, 64);
    l1acc[rr] = v1; l2acc[rr] = v2;
  }

  float sw[4];
  #pragma unroll
  for (int nt=0; nt<4; ++nt) sw[nt] = subw[nt*16 + l15];

  #pragma unroll
  for (int rr=0; rr<4; ++rr){
    const int row = quad*4 + rr;
    const float il1 = 1.f / l1acc[rr];
    const float cl2 = lam / l2acc[rr];
    float o[4]; float ss = 0.f;
    #pragma unroll
    for (int nt=0; nt<4; ++nt){
      o[nt] = O1[nt][rr]*il1 - O2[nt][rr]*cl2;
      ss += o[nt]*o[nt];
    }
    ss += __shfl_xor(ss, 1, 64);
    ss += __shfl_xor(ss, 2, 64);
    ss += __shfl_xor(ss, 4, 64);
    ss += __shfl_xor(ss, 8, 64);
    const float rs = rsqrtf(ss*(1.f/64.f) + 1e-5f) * 0.8f;
    const int orow = b*1024 + qt*64 + wave*16 + row;
    u16* op = out + (size_t)orow*512 + h*64 + l15;
    #pragma unroll
    for (int nt=0; nt<4; ++nt)
      op[nt*16] = f2bf(o[nt]*rs*sw[nt]);
  }
}

// ---------------------------------------------------------------------------
extern "C" void kernel_launch(void* const* d_in, const int* in_sizes, int n_in,
                              void* d_out, int out_size, void* d_ws, size_t ws_size,
                              hipStream_t stream)
{
  (void)in_sizes; (void)n_in; (void)out_size; (void)ws_size;
  const float* x    = (const float*)d_in[0];
  const float* Wq   = (const float*)d_in[1];
  const float* Wk   = (const float*)d_in[2];
  const float* Wv   = (const float*)d_in[3];
  const float* Wo   = (const float*)d_in[4];
  const float* lq1  = (const float*)d_in[5];
  const float* lk1  = (const float*)d_in[6];
  const float* lq2  = (const float*)d_in[7];
  const float* lk2  = (const float*)d_in[8];
  const float* subw = (const float*)d_in[9];
  const float* n1w  = (const float*)d_in[10];
  const float* n1b  = (const float*)d_in[11];
  const float* n2w  = (const float*)d_in[12];
  const float* n2b  = (const float*)d_in[13];
  const float* m1w  = (const float*)d_in[14];
  const float* m1b  = (const float*)d_in[15];
  const float* mW1  = (const float*)d_in[16];
  const float* mb1  = (const float*)d_in[17];
  const float* m2w  = (const float*)d_in[18];
  const float* m2b  = (const float*)d_in[19];
  const float* mW2  = (const float*)d_in[20];
  const float* mb2  = (const float*)d_in[21];
  float* out = (float*)d_out;   // fp32 output

  char* ws = (char*)d_ws;
  const size_t MB = (size_t)1 << 20;
  u16*  xn  = (u16*)(ws + 0*MB);
  u16*  qkv = (u16*)(ws + 8*MB);    // [8192][1536] bf16 = 24 MB -> [8,32)
  u16*  a   = (u16*)(ws + 0*MB);    // attn out, reuse xn
  u16*  ao  = (u16*)(ws + 8*MB);    // reuse qkv (dead after attn)
  u16*  z1  = (u16*)(ws + 16*MB);
  float* h  = (float*)(ws + 32*MB);
  u16*  vt  = (u16*)(ws + 32*MB);   // Vt[64][64][1024]; dead before h written
  u16*  t   = (u16*)(ws + 48*MB);   // [48,80), LN2048 in place
  u16* Wqkvb= (u16*)(ws + 80*MB);   // [1536][512] bf16 = 1.5 MB
  u16* Wob  = (u16*)(ws + 81*MB + 512*1024);
  u16* W1b  = (u16*)(ws + 82*MB);
  u16* W2b  = (u16*)(ws + 84*MB);

  const int M = 8192;

  cvt_all<<<1536, 256, 0, stream>>>(Wq, Wk, Wv, Wo, mW1, mW2, Wqkvb, Wob, W1b, W2b);

  ln512_kernel<<<2048, 256, 0, stream>>>(x, n1w, n1b, xn);

  gemm_bt<EPI_NONE,u16><<<dim3(12,64), 256, 0, stream>>>(xn, Wqkvb, nullptr, nullptr, qkv, M, 1536, 512);

  transpose_v<<<1024, 256, 0, stream>>>(qkv, vt);

  attn_mfma<<<1024, 256, 0, stream>>>(qkv, vt, lq1, lk1, lq2, lk2, subw, a);

  gemm_bt<EPI_NONE,u16><<<dim3(4,64), 256, 0, stream>>>(a, Wob, nullptr, nullptr, ao, M, 512, 512);

  lnres_kernel<<<2048, 256, 0, stream>>>(ao, x, n2w, n2b, m1w, m1b, h, z1);

  gemm_bt<EPI_BIAS_GELU,u16><<<dim3(16,64), 256, 0, stream>>>(z1, W1b, mb1, nullptr, t, M, 2048, 512);

  ln2048_kernel<<<2048, 256, 0, stream>>>(t, m2w, m2b, t);

  gemm_bt<EPI_BIAS_RES,float><<<dim3(4,64), 256, 0, stream>>>(t, W2b, mb2, h, out, M, 512, 2048);
}

// Round 7
// 318.405 us; speedup vs baseline: 1.3487x; 1.0144x over previous
//
#include <hip/hip_runtime.h>
#include <cstdint>
#include <cstddef>

typedef unsigned short u16;
typedef unsigned int   u32;
typedef __attribute__((ext_vector_type(8))) short short8;
typedef __attribute__((ext_vector_type(4))) float floatx4;

__device__ __forceinline__ float asf(u32 u){ union{u32 u; float f;} v; v.u=u; return v.f; }
__device__ __forceinline__ u32 asu(float f){ union{float f; u32 u;} v; v.f=f; return v.u; }
__device__ __forceinline__ u16 f2bf(float f){ u32 u = asu(f); u32 r = u + 0x7FFFu + ((u>>16)&1u); return (u16)(r>>16); }
// fast bf16: round-to-nearest, ties away (2 VALU ops)
__device__ __forceinline__ u16 f2bf_fast(float f){ return (u16)((asu(f) + 0x8000u)>>16); }
__device__ __forceinline__ u32 pack2(float a, float b){ return (u32)f2bf(a) | (((u32)f2bf(b))<<16); }
__device__ __forceinline__ void bf8f(uint4 d, float* o){
  o[0]=asf(d.x<<16); o[1]=asf(d.x&0xFFFF0000u);
  o[2]=asf(d.y<<16); o[3]=asf(d.y&0xFFFF0000u);
  o[4]=asf(d.z<<16); o[5]=asf(d.z&0xFFFF0000u);
  o[6]=asf(d.w<<16); o[7]=asf(d.w&0xFFFF0000u);
}

// ---------------------------------------------------------------------------
// fp32 -> bf16 weight conversion, ALL weights in one launch.
// ---------------------------------------------------------------------------
__global__ __launch_bounds__(256) void cvt_all(
    const float* __restrict__ Wq, const float* __restrict__ Wk,
    const float* __restrict__ Wv, const float* __restrict__ Wo,
    const float* __restrict__ W1, const float* __restrict__ W2,
    u16* __restrict__ Wqkv, u16* __restrict__ Wob,
    u16* __restrict__ W1b, u16* __restrict__ W2b)
{
  const int blk = blockIdx.x;
  const float* src; u16* dst; int off;
  if      (blk < 128)  { src = Wq; dst = Wqkv;          off = blk; }
  else if (blk < 256)  { src = Wk; dst = Wqkv + 262144; off = blk - 128; }
  else if (blk < 384)  { src = Wv; dst = Wqkv + 524288; off = blk - 256; }
  else if (blk < 512)  { src = Wo; dst = Wob;           off = blk - 384; }
  else if (blk < 1024) { src = W1; dst = W1b;           off = blk - 512; }
  else                 { src = W2; dst = W2b;           off = blk - 1024; }
  const int i = (off*256 + threadIdx.x)*8;
  const float4 a = *(const float4*)(src + i);
  const float4 b = *(const float4*)(src + i + 4);
  uint4 st;
  st.x = pack2(a.x, a.y); st.y = pack2(a.z, a.w);
  st.z = pack2(b.x, b.y); st.w = pack2(b.z, b.w);
  *(uint4*)(dst + i) = st;
}

// ---------------------------------------------------------------------------
// MFMA GEMM: C[M,N] = A[M,K] @ B[N,K]^T, bf16 in, fp32 accum.
// R15: BM x 128 tile (BM=64 default), BK=32, double-buffered K-steps
// (R11/R14-verified pattern), ONE barrier per step. BM=64 -> grid 2x..8x
// blocks/CU (LDS 24 KB -> 6 blocks/CU cap) so cross-block wave overlap
// hides each block's barrier drain. Wave = (BM/2) x 64.
// ---------------------------------------------------------------------------
enum { EPI_NONE=0, EPI_BIAS_GELU=1, EPI_BIAS_RES=2 };

template<int BM, int EPI, typename OutT>
__global__ __launch_bounds__(256) void gemm_bt(
    const u16* __restrict__ A, const u16* __restrict__ B,
    const float* __restrict__ bias, const float* __restrict__ res,
    OutT* __restrict__ C, int M, int N, int K)
{
  __shared__ u16 As[2][BM*32];
  __shared__ u16 Bs[2][128*32];
  const int tid  = threadIdx.x;
  const int wave = tid >> 6;
  const int lane = tid & 63;
  const int bm = blockIdx.y, bn = blockIdx.x;

  const int srow = wave*16 + (lane>>2);
  const int scol = (lane&3)*8;
  const u16* Ag = A + (size_t)bm*BM*K;
  const u16* Bg = B + (size_t)bn*128*K;

  constexpr int WM = BM/2;          // wave M extent (64 or 32)
  constexpr int MI = WM/16;         // A-frag count (4 or 2)
  const int wm = (wave>>1)*WM;
  const int wn = (wave&1)*64;
  const int fr = lane & 15;
  const int fk = (lane>>4)*8;

  floatx4 acc[MI][4] = {};

  #define G_STAGE(buf, kk)                                                        \
    do {                                                                          \
      if constexpr (BM == 128) {                                                  \
        _Pragma("unroll")                                                         \
        for (int tt = 0; tt < 2; ++tt)                                            \
          __builtin_amdgcn_global_load_lds(                                       \
              (__attribute__((address_space(1))) void*)(Ag + (tt*64 + srow)*K + (kk) + scol), \
              (__attribute__((address_space(3))) void*)(&As[buf][(tt*64 + wave*16)*32]),      \
              16, 0, 0);                                                          \
      } else {                                                                    \
        __builtin_amdgcn_global_load_lds(                                         \
            (__attribute__((address_space(1))) void*)(Ag + srow*K + (kk) + scol), \
            (__attribute__((address_space(3))) void*)(&As[buf][wave*16*32]),      \
            16, 0, 0);                                                            \
      }                                                                           \
      _Pragma("unroll")                                                           \
      for (int tt = 0; tt < 2; ++tt)                                              \
        __builtin_amdgcn_global_load_lds(                                         \
            (__attribute__((address_space(1))) void*)(Bg + (tt*64 + srow)*K + (kk) + scol), \
            (__attribute__((address_space(3))) void*)(&Bs[buf][(tt*64 + wave*16)*32]),      \
            16, 0, 0);                                                            \
    } while (0)

  // prologue: stage k0=0 into buf 0; barrier drains vmcnt
  G_STAGE(0, 0);
  __syncthreads();

  const int nsteps = K >> 5;
  for (int s = 0; s < nsteps; ++s) {
    const int cur = s & 1;
    if (s + 1 < nsteps) G_STAGE(cur^1, (s+1)*32);

    short8 af[MI], bfr[4];
    #pragma unroll
    for (int i=0;i<MI;i++) af[i] = *(const short8*)(&As[cur][(wm + i*16 + fr)*32 + fk]);
    #pragma unroll
    for (int j=0;j<4;j++) bfr[j] = *(const short8*)(&Bs[cur][(wn + j*16 + fr)*32 + fk]);
    #pragma unroll
    for (int i=0;i<MI;i++)
      #pragma unroll
      for (int j=0;j<4;j++)
        acc[i][j] = __builtin_amdgcn_mfma_f32_16x16x32_bf16(af[i], bfr[j], acc[i][j], 0, 0, 0);

    // one barrier: staging for s+1 complete (vmcnt drain) + all waves done
    // reading buf[cur] before it is overwritten at step s+1
    if (s + 1 < nsteps) __syncthreads();
  }
  #undef G_STAGE

  const int col0 = bn*128 + wn + fr;
  float bv[4] = {0.f,0.f,0.f,0.f};
  if constexpr (EPI != EPI_NONE) {
    #pragma unroll
    for (int j=0;j<4;j++) bv[j] = bias[col0 + j*16];
  }
  const int rq = (lane>>4)*4;
  #pragma unroll
  for (int i=0;i<MI;i++){
    #pragma unroll
    for (int rr=0;rr<4;rr++){
      const int m = bm*BM + wm + i*16 + rq + rr;
      const size_t rowoff = (size_t)m*N;
      #pragma unroll
      for (int j=0;j<4;j++){
        float vv = acc[i][j][rr];
        const int n = col0 + j*16;
        if constexpr (EPI == EPI_BIAS_GELU){
          vv += bv[j];
          vv = 0.5f*vv*(1.f + erff(vv*0.70710678118654752f));
        } else if constexpr (EPI == EPI_BIAS_RES){
          vv += bv[j] + res[rowoff + n];
        }
        if constexpr (sizeof(OutT) == 2) C[rowoff + n] = f2bf(vv);
        else                             C[rowoff + n] = vv;
      }
    }
  }
}

// ---------------------------------------------------------------------------
// LayerNorm over 512 (fp32 in, bf16 out), wave-per-row, 4 rows/block
// ---------------------------------------------------------------------------
__global__ __launch_bounds__(256) void ln512_kernel(
    const float* __restrict__ x, const float* __restrict__ w, const float* __restrict__ b,
    u16* __restrict__ out)
{
  const int row  = blockIdx.x*4 + (threadIdx.x>>6);
  const int lane = threadIdx.x & 63;
  const size_t base = (size_t)row*512 + lane*8;
  float v[8];
  { const float4 a = *(const float4*)(x + base);
    const float4 c = *(const float4*)(x + base + 4);
    v[0]=a.x; v[1]=a.y; v[2]=a.z; v[3]=a.w; v[4]=c.x; v[5]=c.y; v[6]=c.z; v[7]=c.w; }
  float s=0.f, sq=0.f;
  #pragma unroll
  for (int i=0;i<8;i++){ s += v[i]; sq += v[i]*v[i]; }
  for (int off=32; off>0; off>>=1){ s += __shfl_xor(s, off, 64); sq += __shfl_xor(sq, off, 64); }
  const float mu = s*(1.f/512.f);
  const float rs = rsqrtf(sq*(1.f/512.f) - mu*mu + 1e-5f);
  float o[8];
  #pragma unroll
  for (int i=0;i<8;i++)
    o[i] = (v[i]-mu)*rs*w[lane*8+i] + b[lane*8+i];
  uint4 st; st.x=pack2(o[0],o[1]); st.y=pack2(o[2],o[3]); st.z=pack2(o[4],o[5]); st.w=pack2(o[6],o[7]);
  *(uint4*)(out + base) = st;
}

// h = LN(ao)*w2+b2 + x (fp32 out) ; z = LN(h)*w3+b3 (bf16 out)
__global__ __launch_bounds__(256) void lnres_kernel(
    const u16* __restrict__ ao, const float* __restrict__ x,
    const float* __restrict__ w2, const float* __restrict__ b2,
    const float* __restrict__ w3, const float* __restrict__ b3,
    float* __restrict__ h, u16* __restrict__ z)
{
  const int row  = blockIdx.x*4 + (threadIdx.x>>6);
  const int lane = threadIdx.x & 63;
  const size_t base = (size_t)row*512 + lane*8;
  float a[8], xr[8];
  bf8f(*(const uint4*)(ao + base), a);
  { const float4 p = *(const float4*)(x + base);
    const float4 q = *(const float4*)(x + base + 4);
    xr[0]=p.x; xr[1]=p.y; xr[2]=p.z; xr[3]=p.w; xr[4]=q.x; xr[5]=q.y; xr[6]=q.z; xr[7]=q.w; }
  float s=0.f, sq=0.f;
  #pragma unroll
  for (int i=0;i<8;i++){ s += a[i]; sq += a[i]*a[i]; }
  for (int off=32; off>0; off>>=1){ s += __shfl_xor(s, off, 64); sq += __shfl_xor(sq, off, 64); }
  float mu = s*(1.f/512.f);
  float rs = rsqrtf(sq*(1.f/512.f) - mu*mu + 1e-5f);
  float hv[8];
  #pragma unroll
  for (int i=0;i<8;i++)
    hv[i] = (a[i]-mu)*rs*w2[lane*8+i] + b2[lane*8+i] + xr[i];
  { float4 p; p.x=hv[0]; p.y=hv[1]; p.z=hv[2]; p.w=hv[3];
    float4 q; q.x=hv[4]; q.y=hv[5]; q.z=hv[6]; q.w=hv[7];
    *(float4*)(h + base) = p; *(float4*)(h + base + 4) = q; }
  s=0.f; sq=0.f;
  #pragma unroll
  for (int i=0;i<8;i++){ s += hv[i]; sq += hv[i]*hv[i]; }
  for (int off=32; off>0; off>>=1){ s += __shfl_xor(s, off, 64); sq += __shfl_xor(sq, off, 64); }
  mu = s*(1.f/512.f);
  rs = rsqrtf(sq*(1.f/512.f) - mu*mu + 1e-5f);
  float zv[8];
  #pragma unroll
  for (int i=0;i<8;i++)
    zv[i] = (hv[i]-mu)*rs*w3[lane*8+i] + b3[lane*8+i];
  uint4 st; st.x=pack2(zv[0],zv[1]); st.y=pack2(zv[2],zv[3]); st.z=pack2(zv[4],zv[5]); st.w=pack2(zv[6],zv[7]);
  *(uint4*)(z + base) = st;
}

// LayerNorm over 2048 (bf16, in place safe)
__global__ __launch_bounds__(256) void ln2048_kernel(
    const u16* x, const float* __restrict__ w, const float* __restrict__ b,
    u16* out)
{
  const int row  = blockIdx.x*4 + (threadIdx.x>>6);
  const int lane = threadIdx.x & 63;
  const u16* xp = x + (size_t)row*2048;
  float v[32];
  #pragma unroll
  for (int g=0; g<4; ++g) bf8f(*(const uint4*)(xp + g*512 + lane*8), v + g*8);
  float s=0.f, sq=0.f;
  #pragma unroll
  for (int i=0;i<32;i++){ s += v[i]; sq += v[i]*v[i]; }
  for (int off=32; off>0; off>>=1){ s += __shfl_xor(s, off, 64); sq += __shfl_xor(sq, off, 64); }
  const float mu = s*(1.f/2048.f);
  const float rs = rsqrtf(sq*(1.f/2048.f) - mu*mu + 1e-5f);
  u16* op = out + (size_t)row*2048;
  #pragma unroll
  for (int g=0; g<4; ++g){
    float o[8];
    #pragma unroll
    for (int i=0;i<8;i++){
      const int idx = g*512 + lane*8 + i;
      o[i] = (v[g*8+i]-mu)*rs*w[idx] + b[idx];
    }
    uint4 st; st.x=pack2(o[0],o[1]); st.y=pack2(o[2],o[3]); st.z=pack2(o[4],o[5]); st.w=pack2(o[6],o[7]);
    *(uint4*)(op + g*512 + lane*8) = st;
  }
}

// ---------------------------------------------------------------------------
// V transpose: QKV[8192 tok][1536] (v at col 1024) -> Vt[bh 64][dim 64][key 1024].
// ---------------------------------------------------------------------------
__global__ __launch_bounds__(256) void transpose_v(
    const u16* __restrict__ QKV, u16* __restrict__ Vt)
{
  __shared__ __align__(16) u16 T[64][72];
  const int bid = blockIdx.x;
  const int bh  = bid >> 4;
  const int kt  = bid & 15;
  const int b   = bh >> 3;
  const int h   = bh & 7;
  const int tid = threadIdx.x;

  const int key = tid >> 2;
  const int dc  = (tid & 3) * 16;
  const u16* src = QKV + ((size_t)(b*1024 + kt*64 + key))*1536 + 1024 + h*64 + dc;
  const uint4 a0 = *(const uint4*)(src);
  const uint4 a1 = *(const uint4*)(src + 8);
  *(uint4*)(&T[key][dc])     = a0;
  *(uint4*)(&T[key][dc + 8]) = a1;
  __syncthreads();

  const int d  = tid >> 2;
  const int kc = (tid & 3) * 16;
  union { uint4 q[2]; u16 us[16]; } ow;
  #pragma unroll
  for (int i=0;i<16;i++) ow.us[i] = T[kc + i][d];
  u16* dst = Vt + ((size_t)(bh*64 + d))*1024 + kt*64 + kc;
  *(uint4*)(dst)     = ow.q[0];
  *(uint4*)(dst + 8) = ow.q[1];
}

// ---------------------------------------------------------------------------
// MFMA differential flash attention — unchanged from R14 (verified).
// ---------------------------------------------------------------------------
#define ATT_SCALE 0.17677669529663687f   // 32^-0.5

__global__ __launch_bounds__(256) void attn_mfma(
    const u16* __restrict__ QKV, const u16* __restrict__ Vt,
    const float* __restrict__ lq1, const float* __restrict__ lk1,
    const float* __restrict__ lq2, const float* __restrict__ lk2,
    const float* __restrict__ subw, u16* __restrict__ out)
{
  __shared__ __align__(16) u16 Ks1[2][64*32];   // [buf][key][dim 0..31]  8 KB
  __shared__ __align__(16) u16 Ks2[2][64*32];   // [buf][key][dim 32..63] 8 KB
  __shared__ __align__(16) u16 Vs [2][64*64];   // [buf][dim][key 0..63] 16 KB
  __shared__ __align__(16) u16 Ps [2][4][16*32];// [sub][wave][row*32]    8 KB

  const int tid  = threadIdx.x;
  const int wave = tid >> 6;
  const int lane = tid & 63;
  const int quad = lane >> 4;
  const int l15  = lane & 15;

  const int bid = blockIdx.x;
  const int bh  = bid >> 4;
  const int qt  = bid & 15;
  const int b   = bh >> 3;
  const int h   = bh & 7;

  float t1 = 0.f, t2 = 0.f;
  for (int i=0;i<32;i++){ t1 += lq1[i]*lk1[i]; t2 += lq2[i]*lk2[i]; }
  const float lam = __expf(t1) - __expf(t2) + 0.2f;   // LAMBDA_INIT = 0.2

  const int qrowg = b*1024 + qt*64 + wave*16 + l15;
  const short8 aq1 = *(const short8*)(QKV + (size_t)qrowg*1536 + 2*h*32 + quad*8);
  const short8 aq2 = *(const short8*)(QKV + (size_t)qrowg*1536 + 2*h*32 + 32 + quad*8);

  floatx4 O1[4] = {}, O2[4] = {};
  float l1acc[4] = {0.f,0.f,0.f,0.f};
  float l2acc[4] = {0.f,0.f,0.f,0.f};
  const floatx4 zf4 = {0.f,0.f,0.f,0.f};

  const int kvbase = b*1024;
  u16* pw1 = &Ps[0][wave][0];
  u16* pw2 = &Ps[1][wave][0];

  const int kchunk = ((lane&3) ^ ((lane>>3)&3)) * 8;
  const u16* KbaseS = QKV + (size_t)(kvbase + wave*16 + (lane>>2))*1536 + 512 + 2*h*32 + kchunk;
  const int vchunk = ((lane&7) ^ (lane>>3)) * 8;
  const u16* VbaseS = Vt + ((size_t)bh*64 + wave*16 + (lane>>3))*1024 + vchunk;

  #define STAGE_TILE(buf, tt)                                                     \
    do {                                                                          \
      const u16* kp = KbaseS + (size_t)(tt)*64*1536;                              \
      __builtin_amdgcn_global_load_lds(                                           \
          (__attribute__((address_space(1))) void*)(kp),                          \
          (__attribute__((address_space(3))) void*)(&Ks1[buf][wave*16*32]), 16, 0, 0); \
      __builtin_amdgcn_global_load_lds(                                           \
          (__attribute__((address_space(1))) void*)(kp + 32),                     \
          (__attribute__((address_space(3))) void*)(&Ks2[buf][wave*16*32]), 16, 0, 0); \
      const u16* vp = VbaseS + (tt)*64;                                           \
      __builtin_amdgcn_global_load_lds(                                           \
          (__attribute__((address_space(1))) void*)(vp),                          \
          (__attribute__((address_space(3))) void*)(&Vs[buf][wave*16*64]), 16, 0, 0); \
      __builtin_amdgcn_global_load_lds(                                           \
          (__attribute__((address_space(1))) void*)(vp + (size_t)8*1024),         \
          (__attribute__((address_space(3))) void*)(&Vs[buf][(wave*16+8)*64]), 16, 0, 0); \
    } while (0)

  STAGE_TILE(0, 0);
  __syncthreads();

  const int kslotR = (quad ^ ((l15>>1)&3)) * 8;
  const int pslotR = ((quad + (l15>>2)) & 3) * 8;

  for (int t = 0; t < 16; ++t) {
    const int cur = t & 1;

    if (t < 15) STAGE_TILE(cur^1, t+1);

    #pragma unroll
    for (int kh = 0; kh < 2; ++kh) {
      #pragma unroll
      for (int ktl = 0; ktl < 2; ++ktl) {
        const int kt = kh*2 + ktl;
        const short8 bk1 = *(const short8*)(&Ks1[cur][(kt*16 + l15)*32 + kslotR]);
        const short8 bk2 = *(const short8*)(&Ks2[cur][(kt*16 + l15)*32 + kslotR]);
        const floatx4 s1 = __builtin_amdgcn_mfma_f32_16x16x32_bf16(aq1, bk1, zf4, 0, 0, 0);
        const floatx4 s2 = __builtin_amdgcn_mfma_f32_16x16x32_bf16(aq2, bk2, zf4, 0, 0, 0);
        const int wslot = ((ktl*2 + (l15>>3) + quad) & 3)*8;
        u16* d1 = pw1 + wslot + (l15&7);
        u16* d2 = pw2 + wslot + (l15&7);
        #pragma unroll
        for (int rr = 0; rr < 4; ++rr) {
          const float p1 = __expf(s1[rr]*ATT_SCALE);
          const float p2 = __expf(s2[rr]*ATT_SCALE);
          d1[(quad*4+rr)*32] = f2bf_fast(p1);
          d2[(quad*4+rr)*32] = f2bf_fast(p2);
          l1acc[rr] += p1;
          l2acc[rr] += p2;
        }
      }
      const short8 ap1 = *(const short8*)(pw1 + l15*32 + pslotR);
      const short8 ap2 = *(const short8*)(pw2 + l15*32 + pslotR);
      const int vslotR = ((kh*4 + quad) ^ (l15&7)) * 8;
      #pragma unroll
      for (int nt = 0; nt < 4; ++nt) {
        const short8 bv = *(const short8*)(&Vs[cur][(nt*16 + l15)*64 + vslotR]);
        O1[nt] = __builtin_amdgcn_mfma_f32_16x16x32_bf16(ap1, bv, O1[nt], 0, 0, 0);
        O2[nt] = __builtin_amdgcn_mfma_f32_16x16x32_bf16(ap2, bv, O2[nt], 0, 0, 0);
      }
    }

    if (t < 15) __syncthreads();
  }
  #undef STAGE_TILE

  #pragma unroll
  for (int rr=0; rr<4; ++rr){
    float v1 = l1acc[rr], v2 = l2acc[rr];
    v1 += __shfl_xor(v1, 1, 64); v2 += __shfl_xor(v2, 1, 64);
    v1 += __shfl_xor(v1, 2, 64); v2 += __shfl_xor(v2, 2, 64);
    v1 += __shfl_xor(v1, 4, 64); v2 += __shfl_xor(v2, 4, 64);
    v1 += __shfl_xor(v1, 8, 64); v2 += __shfl_xor(v2, 8, 64);
    l1acc[rr] = v1; l2acc[rr] = v2;
  }

  float sw[4];
  #pragma unroll
  for (int nt=0; nt<4; ++nt) sw[nt] = subw[nt*16 + l15];

  #pragma unroll
  for (int rr=0; rr<4; ++rr){
    const int row = quad*4 + rr;
    const float il1 = 1.f / l1acc[rr];
    const float cl2 = lam / l2acc[rr];
    float o[4]; float ss = 0.f;
    #pragma unroll
    for (int nt=0; nt<4; ++nt){
      o[nt] = O1[nt][rr]*il1 - O2[nt][rr]*cl2;
      ss += o[nt]*o[nt];
    }
    ss += __shfl_xor(ss, 1, 64);
    ss += __shfl_xor(ss, 2, 64);
    ss += __shfl_xor(ss, 4, 64);
    ss += __shfl_xor(ss, 8, 64);
    const float rs = rsqrtf(ss*(1.f/64.f) + 1e-5f) * 0.8f;
    const int orow = b*1024 + qt*64 + wave*16 + row;
    u16* op = out + (size_t)orow*512 + h*64 + l15;
    #pragma unroll
    for (int nt=0; nt<4; ++nt)
      op[nt*16] = f2bf(o[nt]*rs*sw[nt]);
  }
}

// ---------------------------------------------------------------------------
extern "C" void kernel_launch(void* const* d_in, const int* in_sizes, int n_in,
                              void* d_out, int out_size, void* d_ws, size_t ws_size,
                              hipStream_t stream)
{
  (void)in_sizes; (void)n_in; (void)out_size; (void)ws_size;
  const float* x    = (const float*)d_in[0];
  const float* Wq   = (const float*)d_in[1];
  const float* Wk   = (const float*)d_in[2];
  const float* Wv   = (const float*)d_in[3];
  const float* Wo   = (const float*)d_in[4];
  const float* lq1  = (const float*)d_in[5];
  const float* lk1  = (const float*)d_in[6];
  const float* lq2  = (const float*)d_in[7];
  const float* lk2  = (const float*)d_in[8];
  const float* subw = (const float*)d_in[9];
  const float* n1w  = (const float*)d_in[10];
  const float* n1b  = (const float*)d_in[11];
  const float* n2w  = (const float*)d_in[12];
  const float* n2b  = (const float*)d_in[13];
  const float* m1w  = (const float*)d_in[14];
  const float* m1b  = (const float*)d_in[15];
  const float* mW1  = (const float*)d_in[16];
  const float* mb1  = (const float*)d_in[17];
  const float* m2w  = (const float*)d_in[18];
  const float* m2b  = (const float*)d_in[19];
  const float* mW2  = (const float*)d_in[20];
  const float* mb2  = (const float*)d_in[21];
  float* out = (float*)d_out;   // fp32 output

  char* ws = (char*)d_ws;
  const size_t MB = (size_t)1 << 20;
  u16*  xn  = (u16*)(ws + 0*MB);
  u16*  qkv = (u16*)(ws + 8*MB);    // [8192][1536] bf16 = 24 MB -> [8,32)
  u16*  a   = (u16*)(ws + 0*MB);    // attn out, reuse xn
  u16*  ao  = (u16*)(ws + 8*MB);    // reuse qkv (dead after attn)
  u16*  z1  = (u16*)(ws + 16*MB);
  float* h  = (float*)(ws + 32*MB);
  u16*  vt  = (u16*)(ws + 32*MB);   // Vt[64][64][1024]; dead before h written
  u16*  t   = (u16*)(ws + 48*MB);   // [48,80), LN2048 in place
  u16* Wqkvb= (u16*)(ws + 80*MB);   // [1536][512] bf16 = 1.5 MB
  u16* Wob  = (u16*)(ws + 81*MB + 512*1024);
  u16* W1b  = (u16*)(ws + 82*MB);
  u16* W2b  = (u16*)(ws + 84*MB);

  const int M = 8192;

  cvt_all<<<1536, 256, 0, stream>>>(Wq, Wk, Wv, Wo, mW1, mW2, Wqkvb, Wob, W1b, W2b);

  ln512_kernel<<<2048, 256, 0, stream>>>(x, n1w, n1b, xn);

  gemm_bt<64,EPI_NONE,u16><<<dim3(12,128), 256, 0, stream>>>(xn, Wqkvb, nullptr, nullptr, qkv, M, 1536, 512);

  transpose_v<<<1024, 256, 0, stream>>>(qkv, vt);

  attn_mfma<<<1024, 256, 0, stream>>>(qkv, vt, lq1, lk1, lq2, lk2, subw, a);

  gemm_bt<64,EPI_NONE,u16><<<dim3(4,128), 256, 0, stream>>>(a, Wob, nullptr, nullptr, ao, M, 512, 512);

  lnres_kernel<<<2048, 256, 0, stream>>>(ao, x, n2w, n2b, m1w, m1b, h, z1);

  gemm_bt<64,EPI_BIAS_GELU,u16><<<dim3(16,128), 256, 0, stream>>>(z1, W1b, mb1, nullptr, t, M, 2048, 512);

  ln2048_kernel<<<2048, 256, 0, stream>>>(t, m2w, m2b, t);

  gemm_bt<64,EPI_BIAS_RES,float><<<dim3(4,128), 256, 0, stream>>>(t, W2b, mb2, h, out, M, 512, 2048);
}

// Round 8
// 305.232 us; speedup vs baseline: 1.4069x; 1.0432x over previous
//
#include <hip/hip_runtime.h>
#include <cstdint>
#include <cstddef>

typedef unsigned short u16;
typedef unsigned int   u32;
typedef __attribute__((ext_vector_type(8))) short short8;
typedef __attribute__((ext_vector_type(4))) float floatx4;

__device__ __forceinline__ float asf(u32 u){ union{u32 u; float f;} v; v.u=u; return v.f; }
__device__ __forceinline__ u32 asu(float f){ union{float f; u32 u;} v; v.f=f; return v.u; }
__device__ __forceinline__ u16 f2bf(float f){ u32 u = asu(f); u32 r = u + 0x7FFFu + ((u>>16)&1u); return (u16)(r>>16); }
// fast bf16: round-to-nearest, ties away (2 VALU ops)
__device__ __forceinline__ u16 f2bf_fast(float f){ return (u16)((asu(f) + 0x8000u)>>16); }
__device__ __forceinline__ u32 pack2(float a, float b){ return (u32)f2bf(a) | (((u32)f2bf(b))<<16); }
__device__ __forceinline__ void bf8f(uint4 d, float* o){
  o[0]=asf(d.x<<16); o[1]=asf(d.x&0xFFFF0000u);
  o[2]=asf(d.y<<16); o[3]=asf(d.y&0xFFFF0000u);
  o[4]=asf(d.z<<16); o[5]=asf(d.z&0xFFFF0000u);
  o[6]=asf(d.w<<16); o[7]=asf(d.w&0xFFFF0000u);
}

// ---------------------------------------------------------------------------
// fp32 -> bf16 weight conversion, ALL weights in one launch.
// ---------------------------------------------------------------------------
__global__ __launch_bounds__(256) void cvt_all(
    const float* __restrict__ Wq, const float* __restrict__ Wk,
    const float* __restrict__ Wv, const float* __restrict__ Wo,
    const float* __restrict__ W1, const float* __restrict__ W2,
    u16* __restrict__ Wqkv, u16* __restrict__ Wob,
    u16* __restrict__ W1b, u16* __restrict__ W2b)
{
  const int blk = blockIdx.x;
  const float* src; u16* dst; int off;
  if      (blk < 128)  { src = Wq; dst = Wqkv;          off = blk; }
  else if (blk < 256)  { src = Wk; dst = Wqkv + 262144; off = blk - 128; }
  else if (blk < 384)  { src = Wv; dst = Wqkv + 524288; off = blk - 256; }
  else if (blk < 512)  { src = Wo; dst = Wob;           off = blk - 384; }
  else if (blk < 1024) { src = W1; dst = W1b;           off = blk - 512; }
  else                 { src = W2; dst = W2b;           off = blk - 1024; }
  const int i = (off*256 + threadIdx.x)*8;
  const float4 a = *(const float4*)(src + i);
  const float4 b = *(const float4*)(src + i + 4);
  uint4 st;
  st.x = pack2(a.x, a.y); st.y = pack2(a.z, a.w);
  st.z = pack2(b.x, b.y); st.w = pack2(b.z, b.w);
  *(uint4*)(dst + i) = st;
}

// ---------------------------------------------------------------------------
// MFMA GEMM: C[M,N] = A[M,K] @ B[N,K]^T, bf16 in, fp32 accum.
// R16: BM x 128 tile, BK=64 (8 K-steps for K=512 -> half the barriers),
// double-buffered (R11-verified 1-barrier/step pattern). LDS rows = 64 u16
// (128 B, 8x16B slots), XOR-swizzled BOTH sides (rule 21 / T2): linear LDS
// dest + pre-swizzled GLOBAL source chunk ((lane&7)^(lane>>3)) + read slot
// ((kk*4+quad)^(fr&7)) -> frag ds_read_b128 conflict-free (was 8-way).
// Pattern identical to attn Vs (verified R11-R15). LDS 48 KB -> 3 blocks/CU.
// ---------------------------------------------------------------------------
enum { EPI_NONE=0, EPI_BIAS_GELU=1, EPI_BIAS_RES=2 };

template<int BM, int EPI, typename OutT>
__global__ __launch_bounds__(256) void gemm_bt(
    const u16* __restrict__ A, const u16* __restrict__ B,
    const float* __restrict__ bias, const float* __restrict__ res,
    OutT* __restrict__ C, int M, int N, int K)
{
  __shared__ u16 As[2][BM*64];    // [buf][row][64], swizzled slots
  __shared__ u16 Bs[2][128*64];
  const int tid  = threadIdx.x;
  const int wave = tid >> 6;
  const int lane = tid & 63;
  const int bm = blockIdx.y, bn = blockIdx.x;

  // staging geometry: each global_load_lds inst moves 8 rows (128 B each);
  // lane -> row +(lane>>3), source 16B chunk ((lane&7)^(lane>>3)) [pre-swizzle]
  const int srow8  = lane >> 3;
  const int schunk = ((lane&7) ^ (lane>>3)) * 8;
  const u16* Ag = A + (size_t)bm*BM*K;
  const u16* Bg = B + (size_t)bn*128*K;

  constexpr int WM = BM/2;          // wave M extent
  constexpr int MI = WM/16;         // A-frag count
  const int wm = (wave>>1)*WM;
  const int wn = (wave&1)*64;
  const int fr = lane & 15;
  const int quad = lane >> 4;

  floatx4 acc[MI][4] = {};

  #define G_STAGE(buf, koff)                                                      \
    do {                                                                          \
      _Pragma("unroll")                                                           \
      for (int ii = 0; ii < BM/32; ++ii)                                          \
        __builtin_amdgcn_global_load_lds(                                         \
            (__attribute__((address_space(1))) void*)(Ag + (size_t)(wave*(BM/4) + ii*8 + srow8)*K + (koff) + schunk), \
            (__attribute__((address_space(3))) void*)(&As[buf][(wave*(BM/4) + ii*8)*64]), \
            16, 0, 0);                                                            \
      _Pragma("unroll")                                                           \
      for (int ii = 0; ii < 4; ++ii)                                              \
        __builtin_amdgcn_global_load_lds(                                         \
            (__attribute__((address_space(1))) void*)(Bg + (size_t)(wave*32 + ii*8 + srow8)*K + (koff) + schunk), \
            (__attribute__((address_space(3))) void*)(&Bs[buf][(wave*32 + ii*8)*64]), \
            16, 0, 0);                                                            \
    } while (0)

  // prologue: stage k-block 0 into buf 0; barrier drains vmcnt
  G_STAGE(0, 0);
  __syncthreads();

  const int nsteps = K >> 6;
  for (int s = 0; s < nsteps; ++s) {
    const int cur = s & 1;
    if (s + 1 < nsteps) G_STAGE(cur^1, (s+1)*64);

    short8 af[2][MI], bfr[2][4];
    #pragma unroll
    for (int kk=0; kk<2; ++kk){
      #pragma unroll
      for (int i=0;i<MI;i++){
        const int row = wm + i*16 + fr;
        af[kk][i] = *(const short8*)(&As[cur][row*64 + (((kk*4+quad) ^ (fr&7))*8)]);
      }
      #pragma unroll
      for (int j=0;j<4;j++){
        const int row = wn + j*16 + fr;
        bfr[kk][j] = *(const short8*)(&Bs[cur][row*64 + (((kk*4+quad) ^ (fr&7))*8)]);
      }
    }
    #pragma unroll
    for (int kk=0; kk<2; ++kk)
      #pragma unroll
      for (int i=0;i<MI;i++)
        #pragma unroll
        for (int j=0;j<4;j++)
          acc[i][j] = __builtin_amdgcn_mfma_f32_16x16x32_bf16(af[kk][i], bfr[kk][j], acc[i][j], 0, 0, 0);

    // one barrier: staging for s+1 complete (vmcnt drain) + all waves done
    // reading buf[cur] before it is overwritten at step s+1
    if (s + 1 < nsteps) __syncthreads();
  }
  #undef G_STAGE

  const int col0 = bn*128 + wn + fr;
  float bv[4] = {0.f,0.f,0.f,0.f};
  if constexpr (EPI != EPI_NONE) {
    #pragma unroll
    for (int j=0;j<4;j++) bv[j] = bias[col0 + j*16];
  }
  const int rq = (lane>>4)*4;
  #pragma unroll
  for (int i=0;i<MI;i++){
    #pragma unroll
    for (int rr=0;rr<4;rr++){
      const int m = bm*BM + wm + i*16 + rq + rr;
      const size_t rowoff = (size_t)m*N;
      #pragma unroll
      for (int j=0;j<4;j++){
        float vv = acc[i][j][rr];
        const int n = col0 + j*16;
        if constexpr (EPI == EPI_BIAS_GELU){
          vv += bv[j];
          vv = 0.5f*vv*(1.f + erff(vv*0.70710678118654752f));
        } else if constexpr (EPI == EPI_BIAS_RES){
          vv += bv[j] + res[rowoff + n];
        }
        if constexpr (sizeof(OutT) == 2) C[rowoff + n] = f2bf(vv);
        else                             C[rowoff + n] = vv;
      }
    }
  }
}

// ---------------------------------------------------------------------------
// LayerNorm over 512 (fp32 in, bf16 out), wave-per-row, 4 rows/block
// ---------------------------------------------------------------------------
__global__ __launch_bounds__(256) void ln512_kernel(
    const float* __restrict__ x, const float* __restrict__ w, const float* __restrict__ b,
    u16* __restrict__ out)
{
  const int row  = blockIdx.x*4 + (threadIdx.x>>6);
  const int lane = threadIdx.x & 63;
  const size_t base = (size_t)row*512 + lane*8;
  float v[8];
  { const float4 a = *(const float4*)(x + base);
    const float4 c = *(const float4*)(x + base + 4);
    v[0]=a.x; v[1]=a.y; v[2]=a.z; v[3]=a.w; v[4]=c.x; v[5]=c.y; v[6]=c.z; v[7]=c.w; }
  float s=0.f, sq=0.f;
  #pragma unroll
  for (int i=0;i<8;i++){ s += v[i]; sq += v[i]*v[i]; }
  for (int off=32; off>0; off>>=1){ s += __shfl_xor(s, off, 64); sq += __shfl_xor(sq, off, 64); }
  const float mu = s*(1.f/512.f);
  const float rs = rsqrtf(sq*(1.f/512.f) - mu*mu + 1e-5f);
  float o[8];
  #pragma unroll
  for (int i=0;i<8;i++)
    o[i] = (v[i]-mu)*rs*w[lane*8+i] + b[lane*8+i];
  uint4 st; st.x=pack2(o[0],o[1]); st.y=pack2(o[2],o[3]); st.z=pack2(o[4],o[5]); st.w=pack2(o[6],o[7]);
  *(uint4*)(out + base) = st;
}

// h = LN(ao)*w2+b2 + x (fp32 out) ; z = LN(h)*w3+b3 (bf16 out)
__global__ __launch_bounds__(256) void lnres_kernel(
    const u16* __restrict__ ao, const float* __restrict__ x,
    const float* __restrict__ w2, const float* __restrict__ b2,
    const float* __restrict__ w3, const float* __restrict__ b3,
    float* __restrict__ h, u16* __restrict__ z)
{
  const int row  = blockIdx.x*4 + (threadIdx.x>>6);
  const int lane = threadIdx.x & 63;
  const size_t base = (size_t)row*512 + lane*8;
  float a[8], xr[8];
  bf8f(*(const uint4*)(ao + base), a);
  { const float4 p = *(const float4*)(x + base);
    const float4 q = *(const float4*)(x + base + 4);
    xr[0]=p.x; xr[1]=p.y; xr[2]=p.z; xr[3]=p.w; xr[4]=q.x; xr[5]=q.y; xr[6]=q.z; xr[7]=q.w; }
  float s=0.f, sq=0.f;
  #pragma unroll
  for (int i=0;i<8;i++){ s += a[i]; sq += a[i]*a[i]; }
  for (int off=32; off>0; off>>=1){ s += __shfl_xor(s, off, 64); sq += __shfl_xor(sq, off, 64); }
  float mu = s*(1.f/512.f);
  float rs = rsqrtf(sq*(1.f/512.f) - mu*mu + 1e-5f);
  float hv[8];
  #pragma unroll
  for (int i=0;i<8;i++)
    hv[i] = (a[i]-mu)*rs*w2[lane*8+i] + b2[lane*8+i] + xr[i];
  { float4 p; p.x=hv[0]; p.y=hv[1]; p.z=hv[2]; p.w=hv[3];
    float4 q; q.x=hv[4]; q.y=hv[5]; q.z=hv[6]; q.w=hv[7];
    *(float4*)(h + base) = p; *(float4*)(h + base + 4) = q; }
  s=0.f; sq=0.f;
  #pragma unroll
  for (int i=0;i<8;i++){ s += hv[i]; sq += hv[i]*hv[i]; }
  for (int off=32; off>0; off>>=1){ s += __shfl_xor(s, off, 64); sq += __shfl_xor(sq, off, 64); }
  mu = s*(1.f/512.f);
  rs = rsqrtf(sq*(1.f/512.f) - mu*mu + 1e-5f);
  float zv[8];
  #pragma unroll
  for (int i=0;i<8;i++)
    zv[i] = (hv[i]-mu)*rs*w3[lane*8+i] + b3[lane*8+i];
  uint4 st; st.x=pack2(zv[0],zv[1]); st.y=pack2(zv[2],zv[3]); st.z=pack2(zv[4],zv[5]); st.w=pack2(zv[6],zv[7]);
  *(uint4*)(z + base) = st;
}

// LayerNorm over 2048 (bf16, in place safe)
__global__ __launch_bounds__(256) void ln2048_kernel(
    const u16* x, const float* __restrict__ w, const float* __restrict__ b,
    u16* out)
{
  const int row  = blockIdx.x*4 + (threadIdx.x>>6);
  const int lane = threadIdx.x & 63;
  const u16* xp = x + (size_t)row*2048;
  float v[32];
  #pragma unroll
  for (int g=0; g<4; ++g) bf8f(*(const uint4*)(xp + g*512 + lane*8), v + g*8);
  float s=0.f, sq=0.f;
  #pragma unroll
  for (int i=0;i<32;i++){ s += v[i]; sq += v[i]*v[i]; }
  for (int off=32; off>0; off>>=1){ s += __shfl_xor(s, off, 64); sq += __shfl_xor(sq, off, 64); }
  const float mu = s*(1.f/2048.f);
  const float rs = rsqrtf(sq*(1.f/2048.f) - mu*mu + 1e-5f);
  u16* op = out + (size_t)row*2048;
  #pragma unroll
  for (int g=0; g<4; ++g){
    float o[8];
    #pragma unroll
    for (int i=0;i<8;i++){
      const int idx = g*512 + lane*8 + i;
      o[i] = (v[g*8+i]-mu)*rs*w[idx] + b[idx];
    }
    uint4 st; st.x=pack2(o[0],o[1]); st.y=pack2(o[2],o[3]); st.z=pack2(o[4],o[5]); st.w=pack2(o[6],o[7]);
    *(uint4*)(op + g*512 + lane*8) = st;
  }
}

// ---------------------------------------------------------------------------
// V transpose: QKV[8192 tok][1536] (v at col 1024) -> Vt[bh 64][dim 64][key 1024].
// ---------------------------------------------------------------------------
__global__ __launch_bounds__(256) void transpose_v(
    const u16* __restrict__ QKV, u16* __restrict__ Vt)
{
  __shared__ __align__(16) u16 T[64][72];
  const int bid = blockIdx.x;
  const int bh  = bid >> 4;
  const int kt  = bid & 15;
  const int b   = bh >> 3;
  const int h   = bh & 7;
  const int tid = threadIdx.x;

  const int key = tid >> 2;
  const int dc  = (tid & 3) * 16;
  const u16* src = QKV + ((size_t)(b*1024 + kt*64 + key))*1536 + 1024 + h*64 + dc;
  const uint4 a0 = *(const uint4*)(src);
  const uint4 a1 = *(const uint4*)(src + 8);
  *(uint4*)(&T[key][dc])     = a0;
  *(uint4*)(&T[key][dc + 8]) = a1;
  __syncthreads();

  const int d  = tid >> 2;
  const int kc = (tid & 3) * 16;
  union { uint4 q[2]; u16 us[16]; } ow;
  #pragma unroll
  for (int i=0;i<16;i++) ow.us[i] = T[kc + i][d];
  u16* dst = Vt + ((size_t)(bh*64 + d))*1024 + kt*64 + kc;
  *(uint4*)(dst)     = ow.q[0];
  *(uint4*)(dst + 8) = ow.q[1];
}

// ---------------------------------------------------------------------------
// MFMA differential flash attention — R16: identical compute to R14/R15
// (verified) + XCD-chunked block swizzle (T1): XCD x owns bh [x*8, x*8+8)
// -> per-XCD K/V working set 2 MB < 4 MB L2 (was 16 MB, thrashing).
// ---------------------------------------------------------------------------
#define ATT_SCALE 0.17677669529663687f   // 32^-0.5

__global__ __launch_bounds__(256) void attn_mfma(
    const u16* __restrict__ QKV, const u16* __restrict__ Vt,
    const float* __restrict__ lq1, const float* __restrict__ lk1,
    const float* __restrict__ lq2, const float* __restrict__ lk2,
    const float* __restrict__ subw, u16* __restrict__ out)
{
  __shared__ __align__(16) u16 Ks1[2][64*32];   // [buf][key][dim 0..31]  8 KB
  __shared__ __align__(16) u16 Ks2[2][64*32];   // [buf][key][dim 32..63] 8 KB
  __shared__ __align__(16) u16 Vs [2][64*64];   // [buf][dim][key 0..63] 16 KB
  __shared__ __align__(16) u16 Ps [2][4][16*32];// [sub][wave][row*32]    8 KB

  const int tid  = threadIdx.x;
  const int wave = tid >> 6;
  const int lane = tid & 63;
  const int quad = lane >> 4;
  const int l15  = lane & 15;

  // XCD-chunked swizzle: dispatcher round-robins bid%8 across XCDs ->
  // give XCD x the 128 blocks of bh in [x*8, x*8+8)  (bijective: 1024=8*128)
  const int bid = blockIdx.x;
  const int bh  = (bid & 7)*8 + ((bid >> 3) >> 4);
  const int qt  = (bid >> 3) & 15;
  const int b   = bh >> 3;
  const int h   = bh & 7;

  float t1 = 0.f, t2 = 0.f;
  for (int i=0;i<32;i++){ t1 += lq1[i]*lk1[i]; t2 += lq2[i]*lk2[i]; }
  const float lam = __expf(t1) - __expf(t2) + 0.2f;   // LAMBDA_INIT = 0.2

  const int qrowg = b*1024 + qt*64 + wave*16 + l15;
  const short8 aq1 = *(const short8*)(QKV + (size_t)qrowg*1536 + 2*h*32 + quad*8);
  const short8 aq2 = *(const short8*)(QKV + (size_t)qrowg*1536 + 2*h*32 + 32 + quad*8);

  floatx4 O1[4] = {}, O2[4] = {};
  float l1acc[4] = {0.f,0.f,0.f,0.f};
  float l2acc[4] = {0.f,0.f,0.f,0.f};
  const floatx4 zf4 = {0.f,0.f,0.f,0.f};

  const int kvbase = b*1024;
  u16* pw1 = &Ps[0][wave][0];
  u16* pw2 = &Ps[1][wave][0];

  const int kchunk = ((lane&3) ^ ((lane>>3)&3)) * 8;
  const u16* KbaseS = QKV + (size_t)(kvbase + wave*16 + (lane>>2))*1536 + 512 + 2*h*32 + kchunk;
  const int vchunk = ((lane&7) ^ (lane>>3)) * 8;
  const u16* VbaseS = Vt + ((size_t)bh*64 + wave*16 + (lane>>3))*1024 + vchunk;

  #define STAGE_TILE(buf, tt)                                                     \
    do {                                                                          \
      const u16* kp = KbaseS + (size_t)(tt)*64*1536;                              \
      __builtin_amdgcn_global_load_lds(                                           \
          (__attribute__((address_space(1))) void*)(kp),                          \
          (__attribute__((address_space(3))) void*)(&Ks1[buf][wave*16*32]), 16, 0, 0); \
      __builtin_amdgcn_global_load_lds(                                           \
          (__attribute__((address_space(1))) void*)(kp + 32),                     \
          (__attribute__((address_space(3))) void*)(&Ks2[buf][wave*16*32]), 16, 0, 0); \
      const u16* vp = VbaseS + (tt)*64;                                           \
      __builtin_amdgcn_global_load_lds(                                           \
          (__attribute__((address_space(1))) void*)(vp),                          \
          (__attribute__((address_space(3))) void*)(&Vs[buf][wave*16*64]), 16, 0, 0); \
      __builtin_amdgcn_global_load_lds(                                           \
          (__attribute__((address_space(1))) void*)(vp + (size_t)8*1024),         \
          (__attribute__((address_space(3))) void*)(&Vs[buf][(wave*16+8)*64]), 16, 0, 0); \
    } while (0)

  STAGE_TILE(0, 0);
  __syncthreads();

  const int kslotR = (quad ^ ((l15>>1)&3)) * 8;
  const int pslotR = ((quad + (l15>>2)) & 3) * 8;

  for (int t = 0; t < 16; ++t) {
    const int cur = t & 1;

    if (t < 15) STAGE_TILE(cur^1, t+1);

    #pragma unroll
    for (int kh = 0; kh < 2; ++kh) {
      #pragma unroll
      for (int ktl = 0; ktl < 2; ++ktl) {
        const int kt = kh*2 + ktl;
        const short8 bk1 = *(const short8*)(&Ks1[cur][(kt*16 + l15)*32 + kslotR]);
        const short8 bk2 = *(const short8*)(&Ks2[cur][(kt*16 + l15)*32 + kslotR]);
        const floatx4 s1 = __builtin_amdgcn_mfma_f32_16x16x32_bf16(aq1, bk1, zf4, 0, 0, 0);
        const floatx4 s2 = __builtin_amdgcn_mfma_f32_16x16x32_bf16(aq2, bk2, zf4, 0, 0, 0);
        const int wslot = ((ktl*2 + (l15>>3) + quad) & 3)*8;
        u16* d1 = pw1 + wslot + (l15&7);
        u16* d2 = pw2 + wslot + (l15&7);
        #pragma unroll
        for (int rr = 0; rr < 4; ++rr) {
          const float p1 = __expf(s1[rr]*ATT_SCALE);
          const float p2 = __expf(s2[rr]*ATT_SCALE);
          d1[(quad*4+rr)*32] = f2bf_fast(p1);
          d2[(quad*4+rr)*32] = f2bf_fast(p2);
          l1acc[rr] += p1;
          l2acc[rr] += p2;
        }
      }
      const short8 ap1 = *(const short8*)(pw1 + l15*32 + pslotR);
      const short8 ap2 = *(const short8*)(pw2 + l15*32 + pslotR);
      const int vslotR = ((kh*4 + quad) ^ (l15&7)) * 8;
      #pragma unroll
      for (int nt = 0; nt < 4; ++nt) {
        const short8 bv = *(const short8*)(&Vs[cur][(nt*16 + l15)*64 + vslotR]);
        O1[nt] = __builtin_amdgcn_mfma_f32_16x16x32_bf16(ap1, bv, O1[nt], 0, 0, 0);
        O2[nt] = __builtin_amdgcn_mfma_f32_16x16x32_bf16(ap2, bv, O2[nt], 0, 0, 0);
      }
    }

    if (t < 15) __syncthreads();
  }
  #undef STAGE_TILE

  #pragma unroll
  for (int rr=0; rr<4; ++rr){
    float v1 = l1acc[rr], v2 = l2acc[rr];
    v1 += __shfl_xor(v1, 1, 64); v2 += __shfl_xor(v2, 1, 64);
    v1 += __shfl_xor(v1, 2, 64); v2 += __shfl_xor(v2, 2, 64);
    v1 += __shfl_xor(v1, 4, 64); v2 += __shfl_xor(v2, 4, 64);
    v1 += __shfl_xor(v1, 8, 64); v2 += __shfl_xor(v2, 8, 64);
    l1acc[rr] = v1; l2acc[rr] = v2;
  }

  float sw[4];
  #pragma unroll
  for (int nt=0; nt<4; ++nt) sw[nt] = subw[nt*16 + l15];

  #pragma unroll
  for (int rr=0; rr<4; ++rr){
    const int row = quad*4 + rr;
    const float il1 = 1.f / l1acc[rr];
    const float cl2 = lam / l2acc[rr];
    float o[4]; float ss = 0.f;
    #pragma unroll
    for (int nt=0; nt<4; ++nt){
      o[nt] = O1[nt][rr]*il1 - O2[nt][rr]*cl2;
      ss += o[nt]*o[nt];
    }
    ss += __shfl_xor(ss, 1, 64);
    ss += __shfl_xor(ss, 2, 64);
    ss += __shfl_xor(ss, 4, 64);
    ss += __shfl_xor(ss, 8, 64);
    const float rs = rsqrtf(ss*(1.f/64.f) + 1e-5f) * 0.8f;
    const int orow = b*1024 + qt*64 + wave*16 + row;
    u16* op = out + (size_t)orow*512 + h*64 + l15;
    #pragma unroll
    for (int nt=0; nt<4; ++nt)
      op[nt*16] = f2bf(o[nt]*rs*sw[nt]);
  }
}

// ---------------------------------------------------------------------------
extern "C" void kernel_launch(void* const* d_in, const int* in_sizes, int n_in,
                              void* d_out, int out_size, void* d_ws, size_t ws_size,
                              hipStream_t stream)
{
  (void)in_sizes; (void)n_in; (void)out_size; (void)ws_size;
  const float* x    = (const float*)d_in[0];
  const float* Wq   = (const float*)d_in[1];
  const float* Wk   = (const float*)d_in[2];
  const float* Wv   = (const float*)d_in[3];
  const float* Wo   = (const float*)d_in[4];
  const float* lq1  = (const float*)d_in[5];
  const float* lk1  = (const float*)d_in[6];
  const float* lq2  = (const float*)d_in[7];
  const float* lk2  = (const float*)d_in[8];
  const float* subw = (const float*)d_in[9];
  const float* n1w  = (const float*)d_in[10];
  const float* n1b  = (const float*)d_in[11];
  const float* n2w  = (const float*)d_in[12];
  const float* n2b  = (const float*)d_in[13];
  const float* m1w  = (const float*)d_in[14];
  const float* m1b  = (const float*)d_in[15];
  const float* mW1  = (const float*)d_in[16];
  const float* mb1  = (const float*)d_in[17];
  const float* m2w  = (const float*)d_in[18];
  const float* m2b  = (const float*)d_in[19];
  const float* mW2  = (const float*)d_in[20];
  const float* mb2  = (const float*)d_in[21];
  float* out = (float*)d_out;   // fp32 output

  char* ws = (char*)d_ws;
  const size_t MB = (size_t)1 << 20;
  u16*  xn  = (u16*)(ws + 0*MB);
  u16*  qkv = (u16*)(ws + 8*MB);    // [8192][1536] bf16 = 24 MB -> [8,32)
  u16*  a   = (u16*)(ws + 0*MB);    // attn out, reuse xn
  u16*  ao  = (u16*)(ws + 8*MB);    // reuse qkv (dead after attn)
  u16*  z1  = (u16*)(ws + 16*MB);
  float* h  = (float*)(ws + 32*MB);
  u16*  vt  = (u16*)(ws + 32*MB);   // Vt[64][64][1024]; dead before h written
  u16*  t   = (u16*)(ws + 48*MB);   // [48,80), LN2048 in place
  u16* Wqkvb= (u16*)(ws + 80*MB);   // [1536][512] bf16 = 1.5 MB
  u16* Wob  = (u16*)(ws + 81*MB + 512*1024);
  u16* W1b  = (u16*)(ws + 82*MB);
  u16* W2b  = (u16*)(ws + 84*MB);

  const int M = 8192;

  cvt_all<<<1536, 256, 0, stream>>>(Wq, Wk, Wv, Wo, mW1, mW2, Wqkvb, Wob, W1b, W2b);

  ln512_kernel<<<2048, 256, 0, stream>>>(x, n1w, n1b, xn);

  gemm_bt<64,EPI_NONE,u16><<<dim3(12,128), 256, 0, stream>>>(xn, Wqkvb, nullptr, nullptr, qkv, M, 1536, 512);

  transpose_v<<<1024, 256, 0, stream>>>(qkv, vt);

  attn_mfma<<<1024, 256, 0, stream>>>(qkv, vt, lq1, lk1, lq2, lk2, subw, a);

  gemm_bt<64,EPI_NONE,u16><<<dim3(4,128), 256, 0, stream>>>(a, Wob, nullptr, nullptr, ao, M, 512, 512);

  lnres_kernel<<<2048, 256, 0, stream>>>(ao, x, n2w, n2b, m1w, m1b, h, z1);

  gemm_bt<64,EPI_BIAS_GELU,u16><<<dim3(16,128), 256, 0, stream>>>(z1, W1b, mb1, nullptr, t, M, 2048, 512);

  ln2048_kernel<<<2048, 256, 0, stream>>>(t, m2w, m2b, t);

  gemm_bt<64,EPI_BIAS_RES,float><<<dim3(4,128), 256, 0, stream>>>(t, W2b, mb2, h, out, M, 512, 2048);
}